// Round 1
// baseline (571.722 us; speedup 1.0000x reference)
//
#include <hip/hip_runtime.h>

// ---------------------------------------------------------------------------
// SpanEncoderCrossAttention, restructured:
//   q = RoPE(hs @ Wq);  qk = 0.125 * q @ Wk_head^T          (small)
//   scores = qk @ X^T                                       (MFMA GEMM, 34 GF)
//   attn = softmax(scores)                                  (in-place bf16)
//   ctx = attn @ X                                          (MFMA GEMM, 34 GF)
//   out = (ctx @ Wv_head) @ Wo                              (small)
// This halves FLOPs vs projecting K/V (137 GF -> 70 GF) because LQ*H << LKV.
// ---------------------------------------------------------------------------

typedef float  f32x4  __attribute__((ext_vector_type(4)));
typedef __bf16 bf16x8 __attribute__((ext_vector_type(8)));

__device__ __forceinline__ ushort f2b(float x) {
  union { float f; unsigned u; } v; v.f = x;
  unsigned r = (v.u + 0x7fffu + ((v.u >> 16) & 1u)) >> 16;
  return (ushort)r;
}
__device__ __forceinline__ void unpack2(unsigned v, float& lo, float& hi) {
  union { unsigned u; float f; } a, b;
  a.u = v << 16; b.u = v & 0xffff0000u;
  lo = a.f; hi = b.f;
}
__device__ __forceinline__ unsigned packb(float a, float b) {
  return (unsigned)f2b(a) | ((unsigned)f2b(b) << 16);
}

__device__ __forceinline__ void gload16(const void* g, void* l) {
  // async global->LDS, 16B per lane, LDS dest = wave-uniform base + lane*16
  __builtin_amdgcn_global_load_lds(
      (const __attribute__((address_space(1))) void*)g,
      (__attribute__((address_space(3))) void*)l, 16, 0, 0);
}

// ---------------------------------------------------------------------------
// K1: cast X (fp32) -> Xb (bf16, [B,4096,1024]) and XbT (bf16, [B,1024,4096])
// 64x64 tiles, LDS transpose. grid (16, 64, 8), 256 thr.
// ---------------------------------------------------------------------------
__global__ __launch_bounds__(256) void cast_transpose(
    const float* __restrict__ X, ushort* __restrict__ Xb, ushort* __restrict__ XbT) {
  const int b  = blockIdx.z;
  const int j0 = blockIdx.y << 6;
  const int c0 = blockIdx.x << 6;
  const int t  = threadIdx.x;
  __shared__ ushort tile[64 * 66];

  const int jr = t >> 2, cc = (t & 3) << 4;
  const float4* src = (const float4*)(X + ((size_t)b * 4096 + j0 + jr) * 1024 + c0 + cc);
  ushort u[16];
#pragma unroll
  for (int q = 0; q < 4; ++q) {
    const float4 v = src[q];
    u[q*4+0] = f2b(v.x); u[q*4+1] = f2b(v.y); u[q*4+2] = f2b(v.z); u[q*4+3] = f2b(v.w);
  }
  ushort* dstN = Xb + ((size_t)b * 4096 + j0 + jr) * 1024 + c0 + cc;
#pragma unroll
  for (int q = 0; q < 4; ++q) {
    ushort4 w; w.x = u[q*4+0]; w.y = u[q*4+1]; w.z = u[q*4+2]; w.w = u[q*4+3];
    ((ushort4*)dstN)[q] = w;
  }
#pragma unroll
  for (int q = 0; q < 16; ++q) tile[jr * 66 + cc + q] = u[q];
  __syncthreads();
  const int cr = t >> 2, jc = (t & 3) << 4;
  ushort o[16];
#pragma unroll
  for (int q = 0; q < 16; ++q) o[q] = tile[(jc + q) * 66 + cr];
  ushort* dstT = XbT + ((size_t)b * 1024 + c0 + cr) * 4096 + j0 + jc;
#pragma unroll
  for (int q = 0; q < 4; ++q) {
    ushort4 w; w.x = o[q*4+0]; w.y = o[q*4+1]; w.z = o[q*4+2]; w.w = o[q*4+3];
    ((ushort4*)dstT)[q] = w;
  }
}

// ---------------------------------------------------------------------------
// K2: per (b,h): q_h = hs[b] @ Wq[:,h*64:+64]; RoPE; qk = 0.125*q_h @ Wk_h^T
// qk layout [B, 512, 1024] bf16 with row m = h*32 + i. grid 128, 256 thr.
// ---------------------------------------------------------------------------
__global__ __launch_bounds__(256) void qk_proj(
    const float* __restrict__ hs, const float* __restrict__ Wq,
    const float* __restrict__ Wk, const int* __restrict__ pos,
    ushort* __restrict__ qk) {
  const int b = blockIdx.x >> 4;
  const int h = blockIdx.x & 15;
  const int t = threadIdx.x;
  __shared__ float s_hs[32 * 132];
  __shared__ float s_w [128 * 68];
  __shared__ float s_qr[32 * 68];

  const int i  = t >> 3;          // 0..31  (query row)
  const int d0 = (t & 7) << 3;    // 0..56  (8 head-dims per thread)

  float acc8[8];
#pragma unroll
  for (int j = 0; j < 8; ++j) acc8[j] = 0.f;

  // ---- phase 1: q_h[i][d] = sum_c hs[b][i][c] * Wq[c][h*64+d] ----
  for (int c0 = 0; c0 < 1024; c0 += 128) {
    __syncthreads();
    {
      const int r = t >> 3, cc = (t & 7) << 4;
      const float4* src = (const float4*)(hs + ((size_t)b * 32 + r) * 1024 + c0 + cc);
      float4* dst = (float4*)&s_hs[r * 132 + cc];
#pragma unroll
      for (int j = 0; j < 4; ++j) dst[j] = src[j];
    }
    {
      const int r = t >> 1, c32 = (t & 1) << 5;
      const float4* src = (const float4*)(Wq + (size_t)(c0 + r) * 1024 + h * 64 + c32);
      float4* dst = (float4*)&s_w[r * 68 + c32];
#pragma unroll
      for (int j = 0; j < 8; ++j) dst[j] = src[j];
    }
    __syncthreads();
    for (int cc = 0; cc < 128; ++cc) {
      const float a = s_hs[i * 132 + cc];
      const float4 w0 = *(const float4*)&s_w[cc * 68 + d0];
      const float4 w1 = *(const float4*)&s_w[cc * 68 + d0 + 4];
      acc8[0] += a * w0.x; acc8[1] += a * w0.y; acc8[2] += a * w0.z; acc8[3] += a * w0.w;
      acc8[4] += a * w1.x; acc8[5] += a * w1.y; acc8[6] += a * w1.z; acc8[7] += a * w1.w;
    }
  }
#pragma unroll
  for (int j = 0; j < 8; ++j) s_qr[i * 68 + d0 + j] = acc8[j];
  __syncthreads();

  // ---- RoPE (query only), fold 1/sqrt(D)=0.125 ----
  // position dtype hedge: if data is int64, all odd 32-bit slots (hi words)
  // are 0; if int32, odd slots are random nonzero positions.
  unsigned oddor = 0;
  for (int j = 1; j < 256; j += 2) oddor |= (unsigned)pos[j];
  const int idx = b * 32 + i;
  const int p   = (oddor == 0) ? pos[2 * idx] : pos[idx];
  const float pf = (float)p;
  float qr8[8];
#pragma unroll
  for (int j = 0; j < 8; ++j) {
    const int d = d0 + j;
    const int f = d & 31;
    const float inv = powf(10000.0f, -(float)f * (1.0f / 32.0f));
    const float ang = pf * inv;
    float sn, cs; sincosf(ang, &sn, &cs);
    const float x  = s_qr[i * 68 + d];
    const float xr = (d < 32) ? -s_qr[i * 68 + d + 32] : s_qr[i * 68 + d - 32];
    qr8[j] = (x * cs + xr * sn) * 0.125f;
  }
  __syncthreads();
#pragma unroll
  for (int j = 0; j < 8; ++j) s_qr[i * 68 + d0 + j] = qr8[j];

  // ---- phase 2: qk[i][c] = sum_d qr[i][d] * Wk[c][h*64+d] ----
  const int cb = t & 7;
  for (int c0 = 0; c0 < 1024; c0 += 128) {
    __syncthreads();
    {
      const int r = t >> 1, c32 = (t & 1) << 5;
      const float4* src = (const float4*)(Wk + (size_t)(c0 + r) * 1024 + h * 64 + c32);
      float4* dst = (float4*)&s_w[r * 68 + c32];
#pragma unroll
      for (int j = 0; j < 8; ++j) dst[j] = src[j];
    }
    __syncthreads();
    float acc16[16];
#pragma unroll
    for (int u = 0; u < 16; ++u) acc16[u] = 0.f;
    for (int d4 = 0; d4 < 16; ++d4) {
      const float4 q4 = *(const float4*)&s_qr[i * 68 + (d4 << 2)];
#pragma unroll
      for (int u = 0; u < 16; ++u) {
        const float4 w4 = *(const float4*)&s_w[(cb + (u << 3)) * 68 + (d4 << 2)];
        acc16[u] += q4.x * w4.x + q4.y * w4.y + q4.z * w4.z + q4.w * w4.w;
      }
    }
    ushort* dst = qk + ((size_t)b * 512 + h * 32 + i) * 1024 + c0 + cb;
#pragma unroll
    for (int u = 0; u < 16; ++u) dst[u << 3] = f2b(acc16[u]);
  }
}

// ---------------------------------------------------------------------------
// G: C[b] = A[b] @ Bt[b]^T  (bf16 in, bf16 out). m97 structure:
// 128x128 block tile, BK=32, 4 waves each 64x64 (4x4 of 16x16x32 MFMA),
// global_load_lds width-16 staging, ds_read_b128 fragments.
// grid (N/128, M/128, B), 256 thr.
// ---------------------------------------------------------------------------
__global__ __launch_bounds__(256) void gemm_bt(
    const ushort* __restrict__ A, const ushort* __restrict__ Bt,
    ushort* __restrict__ C, int M, int N, int K,
    long strideA, long strideB, long strideC) {
  __shared__ alignas(16) ushort sA[128 * 32];
  __shared__ alignas(16) ushort sB[128 * 32];
  const int bz   = blockIdx.z;
  const int m0   = blockIdx.y << 7;
  const int n0   = blockIdx.x << 7;
  const int tid  = threadIdx.x;
  const int wave = tid >> 6, lane = tid & 63;
  const int wm   = wave >> 1, wn = wave & 1;
  const ushort* Ab = A  + (size_t)bz * strideA;
  const ushort* Bb = Bt + (size_t)bz * strideB;

  const int sr = lane >> 2;          // 0..15 row within 16-row chunk
  const int sk = (lane & 3) << 3;    // 0,8,16,24 (k element)

  f32x4 acc[4][4];
#pragma unroll
  for (int a = 0; a < 4; ++a)
#pragma unroll
    for (int c = 0; c < 4; ++c) acc[a][c] = (f32x4){0.f, 0.f, 0.f, 0.f};

  const int fr = lane & 15;
  const int fq = lane >> 4;

  for (int k0 = 0; k0 < K; k0 += 32) {
#pragma unroll
    for (int c = 0; c < 2; ++c) {
      const int r = (wave << 5) + (c << 4) + sr;
      gload16(Ab + (size_t)(m0 + r) * K + k0 + sk, &sA[((wave << 1) + c) << 9]);
      gload16(Bb + (size_t)(n0 + r) * K + k0 + sk, &sB[((wave << 1) + c) << 9]);
    }
    __syncthreads();   // drains vmcnt for global_load_lds
    bf16x8 aF[4], bF[4];
#pragma unroll
    for (int u = 0; u < 4; ++u) {
      aF[u] = *(const bf16x8*)&sA[((wm << 6) + (u << 4) + fr) * 32 + (fq << 3)];
      bF[u] = *(const bf16x8*)&sB[((wn << 6) + (u << 4) + fr) * 32 + (fq << 3)];
    }
#pragma unroll
    for (int mt = 0; mt < 4; ++mt)
#pragma unroll
      for (int nt = 0; nt < 4; ++nt)
        acc[mt][nt] = __builtin_amdgcn_mfma_f32_16x16x32_bf16(
            aF[mt], bF[nt], acc[mt][nt], 0, 0, 0);
    __syncthreads();   // protect LDS before next stage
  }

  ushort* Cb = C + (size_t)bz * strideC;
#pragma unroll
  for (int mt = 0; mt < 4; ++mt)
#pragma unroll
    for (int nt = 0; nt < 4; ++nt)
#pragma unroll
      for (int r = 0; r < 4; ++r) {
        const int row = m0 + (wm << 6) + (mt << 4) + (fq << 2) + r;
        const int col = n0 + (wn << 6) + (nt << 4) + fr;
        Cb[(size_t)row * N + col] = f2b(acc[mt][nt][r]);
      }
}

// ---------------------------------------------------------------------------
// softmax over rows of 4096, in-place on bf16 buffer. grid B*512, 256 thr.
// ---------------------------------------------------------------------------
__global__ __launch_bounds__(256) void softmax_inplace(ushort* __restrict__ S) {
  ushort* s = S + (size_t)blockIdx.x * 4096;
  const int t = threadIdx.x;
  const int lane = t & 63, wv = t >> 6;
  __shared__ float red[4];

  float x[16];
  {
    const uint4 a = *(const uint4*)(s + t * 8);
    const uint4 b = *(const uint4*)(s + 2048 + t * 8);
    unpack2(a.x, x[0], x[1]);  unpack2(a.y, x[2], x[3]);
    unpack2(a.z, x[4], x[5]);  unpack2(a.w, x[6], x[7]);
    unpack2(b.x, x[8], x[9]);  unpack2(b.y, x[10], x[11]);
    unpack2(b.z, x[12], x[13]); unpack2(b.w, x[14], x[15]);
  }
  float mx = -1e30f;
#pragma unroll
  for (int j = 0; j < 16; ++j) mx = fmaxf(mx, x[j]);
  for (int o = 32; o > 0; o >>= 1) mx = fmaxf(mx, __shfl_xor(mx, o));
  if (lane == 0) red[wv] = mx;
  __syncthreads();
  mx = fmaxf(fmaxf(red[0], red[1]), fmaxf(red[2], red[3]));

  float sum = 0.f;
#pragma unroll
  for (int j = 0; j < 16; ++j) { x[j] = expf(x[j] - mx); sum += x[j]; }
  for (int o = 32; o > 0; o >>= 1) sum += __shfl_xor(sum, o);
  __syncthreads();
  if (lane == 0) red[wv] = sum;
  __syncthreads();
  const float inv = 1.0f / (red[0] + red[1] + red[2] + red[3]);

  uint4 o0, o1;
  o0.x = packb(x[0] * inv,  x[1] * inv);  o0.y = packb(x[2] * inv,  x[3] * inv);
  o0.z = packb(x[4] * inv,  x[5] * inv);  o0.w = packb(x[6] * inv,  x[7] * inv);
  o1.x = packb(x[8] * inv,  x[9] * inv);  o1.y = packb(x[10] * inv, x[11] * inv);
  o1.z = packb(x[12] * inv, x[13] * inv); o1.w = packb(x[14] * inv, x[15] * inv);
  *(uint4*)(s + t * 8)        = o0;
  *(uint4*)(s + 2048 + t * 8) = o1;
}

// ---------------------------------------------------------------------------
// K6a: tmp2[b*32+i][h*64+d] = sum_c ctx[b][h*32+i][c] * Wv[c][h*64+d]
// grid 128 (b,h), 256 thr.
// ---------------------------------------------------------------------------
__global__ __launch_bounds__(256) void ctx_wv(
    const ushort* __restrict__ ctx, const float* __restrict__ Wv,
    float* __restrict__ tmp2) {
  const int b = blockIdx.x >> 4, h = blockIdx.x & 15;
  const int t = threadIdx.x;
  __shared__ float s_a[32 * 132];
  __shared__ float s_w[128 * 68];
  const int i = t >> 3, d0 = (t & 7) << 3;
  float acc8[8];
#pragma unroll
  for (int j = 0; j < 8; ++j) acc8[j] = 0.f;

  for (int c0 = 0; c0 < 1024; c0 += 128) {
    __syncthreads();
    {
      const int r = t >> 3, cc = (t & 7) << 4;
      const ushort* src = ctx + ((size_t)b * 512 + h * 32 + r) * 1024 + c0 + cc;
      const uint4 u0 = *(const uint4*)(src);
      const uint4 u1 = *(const uint4*)(src + 8);
      float* dst = &s_a[r * 132 + cc];
      unpack2(u0.x, dst[0], dst[1]);   unpack2(u0.y, dst[2], dst[3]);
      unpack2(u0.z, dst[4], dst[5]);   unpack2(u0.w, dst[6], dst[7]);
      unpack2(u1.x, dst[8], dst[9]);   unpack2(u1.y, dst[10], dst[11]);
      unpack2(u1.z, dst[12], dst[13]); unpack2(u1.w, dst[14], dst[15]);
    }
    {
      const int r = t >> 1, c32 = (t & 1) << 5;
      const float4* src = (const float4*)(Wv + (size_t)(c0 + r) * 1024 + h * 64 + c32);
      float4* dst = (float4*)&s_w[r * 68 + c32];
#pragma unroll
      for (int j = 0; j < 8; ++j) dst[j] = src[j];
    }
    __syncthreads();
    for (int cc = 0; cc < 128; ++cc) {
      const float a = s_a[i * 132 + cc];
      const float4 w0 = *(const float4*)&s_w[cc * 68 + d0];
      const float4 w1 = *(const float4*)&s_w[cc * 68 + d0 + 4];
      acc8[0] += a * w0.x; acc8[1] += a * w0.y; acc8[2] += a * w0.z; acc8[3] += a * w0.w;
      acc8[4] += a * w1.x; acc8[5] += a * w1.y; acc8[6] += a * w1.z; acc8[7] += a * w1.w;
    }
  }
  float* dst = tmp2 + ((size_t)b * 32 + i) * 1024 + h * 64 + d0;
#pragma unroll
  for (int j = 0; j < 8; ++j) dst[j] = acc8[j];
}

// ---------------------------------------------------------------------------
// K6b: out = tmp2 @ Wo : [256,1024]@[1024,1024], fp32. 16x64 tiles,
// grid 256 (16 m-tiles x 16 n-tiles), 256 thr.
// ---------------------------------------------------------------------------
__global__ __launch_bounds__(256) void out_proj(
    const float* __restrict__ A, const float* __restrict__ Wo,
    float* __restrict__ out) {
  const int mt = blockIdx.x >> 4, nt = blockIdx.x & 15;
  const int m0 = mt << 4, n0 = nt << 6;
  const int t  = threadIdx.x;
  __shared__ float sA[16 * 68];
  __shared__ float sW[64 * 68];
  const int n = t & 63, mg = t >> 6;
  float acc[4] = {0.f, 0.f, 0.f, 0.f};

  for (int k0 = 0; k0 < 1024; k0 += 64) {
    __syncthreads();
    {
      const int r = t >> 4, c = (t & 15) << 2;
      *(float4*)&sA[r * 68 + c] = *(const float4*)&A[(size_t)(m0 + r) * 1024 + k0 + c];
    }
    {
      const int r = t >> 2, c = (t & 3) << 4;
      const float4* s = (const float4*)&Wo[(size_t)(k0 + r) * 1024 + n0 + c];
      float4* d = (float4*)&sW[r * 68 + c];
      d[0] = s[0]; d[1] = s[1]; d[2] = s[2]; d[3] = s[3];
    }
    __syncthreads();
    for (int kk = 0; kk < 64; ++kk) {
      const float w = sW[kk * 68 + n];
#pragma unroll
      for (int r = 0; r < 4; ++r) acc[r] += sA[((mg << 2) + r) * 68 + kk] * w;
    }
  }
#pragma unroll
  for (int r = 0; r < 4; ++r)
    out[(size_t)(m0 + (mg << 2) + r) * 1024 + n0 + n] = acc[r];
}

// ---------------------------------------------------------------------------
extern "C" void kernel_launch(void* const* d_in, const int* in_sizes, int n_in,
                              void* d_out, int out_size, void* d_ws, size_t ws_size,
                              hipStream_t stream) {
  const float* hs  = (const float*)d_in[0];
  const float* enc = (const float*)d_in[1];
  const int*   pos = (const int*)d_in[2];
  const float* Wq  = (const float*)d_in[3];
  const float* Wk  = (const float*)d_in[4];
  const float* Wv  = (const float*)d_in[5];
  const float* Wo  = (const float*)d_in[6];
  float* out = (float*)d_out;

  char* w = (char*)d_ws;
  ushort* Xb   = (ushort*)w;  w += (size_t)8 * 4096 * 1024 * 2;   // 67 MB
  ushort* XbT  = (ushort*)w;  w += (size_t)8 * 4096 * 1024 * 2;   // 67 MB
  ushort* qk   = (ushort*)w;  w += (size_t)8 * 512 * 1024 * 2;    // 8.4 MB
  ushort* sc   = (ushort*)w;  w += (size_t)8 * 512 * 4096 * 2;    // 33.5 MB (scores->attn in-place)
  ushort* ctx  = (ushort*)w;  w += (size_t)8 * 512 * 1024 * 2;    // 8.4 MB
  float*  tmp2 = (float*)w;   w += (size_t)256 * 1024 * 4;        // 1 MB

  cast_transpose<<<dim3(16, 64, 8), 256, 0, stream>>>(enc, Xb, XbT);
  qk_proj<<<128, 256, 0, stream>>>(hs, Wq, Wk, pos, qk);
  // scores[b] = qk[b] @ Xb[b]^T : M=512 N=4096 K=1024
  gemm_bt<<<dim3(32, 4, 8), 256, 0, stream>>>(qk, Xb, sc, 512, 4096, 1024,
      (long)512 * 1024, (long)4096 * 1024, (long)512 * 4096);
  softmax_inplace<<<4096, 256, 0, stream>>>(sc);
  // ctx[b] = attn[b] @ XbT[b]^T : M=512 N=1024 K=4096
  gemm_bt<<<dim3(8, 4, 8), 256, 0, stream>>>(sc, XbT, ctx, 512, 1024, 4096,
      (long)512 * 4096, (long)4096 * 1024, (long)512 * 1024);
  ctx_wv<<<128, 256, 0, stream>>>(ctx, Wv, tmp2);
  out_proj<<<256, 256, 0, stream>>>(tmp2, Wo, out);
}

// Round 2
// 554.176 us; speedup vs baseline: 1.0317x; 1.0317x over previous
//
#include <hip/hip_runtime.h>

// ---------------------------------------------------------------------------
// SpanEncoderCrossAttention, restructured (R2):
//   qk = 0.125 * RoPE(hs@Wq) @ Wk_h^T                       (small)
//   scores = qk @ X^T            -> packed layout + row stats in epilogue
//   attn = softmax apply         (combine stats + 1 coalesced pass)
//   ctx  = attn @ X              (K-split x4, fp32 partials)
//   out  = (sum(ctx) @ Wv_head) @ Wo                        (small)
// Key R2 changes vs R1: tile-packed+XOR-swizzled B operands (contiguous 8KB
// staging streams, conflict-free ds_read_b128), batch->XCD grid mapping,
// gemm2 K-split for occupancy, softmax folded into gemm1 epilogue + apply.
// ---------------------------------------------------------------------------

typedef float  f32x4  __attribute__((ext_vector_type(4)));
typedef __bf16 bf16x8 __attribute__((ext_vector_type(8)));

__device__ __forceinline__ ushort f2b(float x) {
  union { float f; unsigned u; } v; v.f = x;
  unsigned r = (v.u + 0x7fffu + ((v.u >> 16) & 1u)) >> 16;
  return (ushort)r;
}
__device__ __forceinline__ float b2f(ushort h) {
  union { unsigned u; float f; } v; v.u = ((unsigned)h) << 16; return v.f;
}
__device__ __forceinline__ void unpack2(unsigned v, float& lo, float& hi) {
  union { unsigned u; float f; } a, b;
  a.u = v << 16; b.u = v & 0xffff0000u;
  lo = a.f; hi = b.f;
}
__device__ __forceinline__ unsigned packb(float a, float b) {
  return (unsigned)f2b(a) | ((unsigned)f2b(b) << 16);
}
__device__ __forceinline__ int swz(int r) { return (r & 3) ^ ((r >> 2) & 3); }

__device__ __forceinline__ void gload16(const void* g, void* l) {
  // async global->LDS, 16B per lane, LDS dest = wave-uniform base + lane*16
  __builtin_amdgcn_global_load_lds(
      (const __attribute__((address_space(1))) void*)g,
      (__attribute__((address_space(3))) void*)l, 16, 0, 0);
}

// ---------------------------------------------------------------------------
// K1: pack X (fp32 [8][4096][1024]) into
//   Xp1[z][jt(32)][ki(32)][r=j&127][p][e]  (gemm1 B: n=j, k=c), and
//   Xp2[z][ct(8)][ki(128)][r=c&127][p][e]  (gemm2 B: n=c, k=j),
// where slot p holds logical 8-elem chunk (p ^ swz(r)).
// Tile 128(j) x 64(c). grid (16 c-tiles, 32 j-tiles, 8 z), 256 thr.
// ---------------------------------------------------------------------------
__global__ __launch_bounds__(256) void pack_x(
    const float* __restrict__ X, ushort* __restrict__ Xp1, ushort* __restrict__ Xp2) {
  const int z = blockIdx.z, jb = blockIdx.y, cb = blockIdx.x;
  const int t = threadIdx.x;
  __shared__ ushort sT[128 * 72];   // [j][c], stride 72 (144B, 16B-aligned)

#pragma unroll
  for (int rep = 0; rep < 2; ++rep) {
    const int j  = rep * 64 + (t >> 2);
    const int c0 = (t & 3) << 4;
    const float4* src = (const float4*)(X + ((size_t)z * 4096 + jb * 128 + j) * 1024 + cb * 64 + c0);
#pragma unroll
    for (int q = 0; q < 4; ++q) {
      const float4 v = src[q];
      ushort4 w; w.x = f2b(v.x); w.y = f2b(v.y); w.z = f2b(v.z); w.w = f2b(v.w);
      *(ushort4*)&sT[j * 72 + c0 + q * 4] = w;
    }
  }
  __syncthreads();

  // Xp1: rows r=j, chunks over c. Wave-contiguous 16B global writes.
  ushort* o1 = Xp1 + ((size_t)(z * 32 + jb) * 32 + cb * 2) * 4096;
#pragma unroll
  for (int q = 0; q < 4; ++q) {
    const int kih = q >> 1;
    const int r   = ((q & 1) << 6) + (t >> 2);
    const int p   = t & 3;
    const int lc  = p ^ swz(r);
    const uint4 v = *(const uint4*)&sT[r * 72 + kih * 32 + lc * 8];
    *(uint4*)&o1[(size_t)kih * 4096 + ((size_t)(q & 1) << 11) + (size_t)t * 8] = v;
  }

  // Xp2: rows r2=c, chunks over j (transposed reads from sT).
  ushort* o2 = Xp2 + (((size_t)(z * 8 + (cb >> 1)) * 128 + jb * 4) * 4096) + ((size_t)(cb & 1) << 11);
#pragma unroll
  for (int q = 0; q < 4; ++q) {
    const int cl = t >> 2;
    const int p2 = t & 3;
    const int lj = p2 ^ swz(cl);
    union { ushort u[8]; uint4 v; } pk;
#pragma unroll
    for (int jj = 0; jj < 8; ++jj) pk.u[jj] = sT[(q * 32 + lj * 8 + jj) * 72 + cl];
    *(uint4*)&o2[(size_t)q * 4096 + (size_t)t * 8] = pk.v;
  }
}

// ---------------------------------------------------------------------------
// K2: per (b,h): q_h = hs[b] @ Wq[:,h*64:+64]; RoPE; qk = 0.125*q_h @ Wk_h^T
// qk layout [B, 512, 1024] bf16 with row m = h*32 + i. grid 128, 256 thr.
// ---------------------------------------------------------------------------
__global__ __launch_bounds__(256) void qk_proj(
    const float* __restrict__ hs, const float* __restrict__ Wq,
    const float* __restrict__ Wk, const int* __restrict__ pos,
    ushort* __restrict__ qk) {
  const int b = blockIdx.x >> 4;
  const int h = blockIdx.x & 15;
  const int t = threadIdx.x;
  __shared__ float s_hs[32 * 132];
  __shared__ float s_w [128 * 68];
  __shared__ float s_qr[32 * 68];

  const int i  = t >> 3;
  const int d0 = (t & 7) << 3;

  float acc8[8];
#pragma unroll
  for (int j = 0; j < 8; ++j) acc8[j] = 0.f;

  for (int c0 = 0; c0 < 1024; c0 += 128) {
    __syncthreads();
    {
      const int r = t >> 3, cc = (t & 7) << 4;
      const float4* src = (const float4*)(hs + ((size_t)b * 32 + r) * 1024 + c0 + cc);
      float4* dst = (float4*)&s_hs[r * 132 + cc];
#pragma unroll
      for (int j = 0; j < 4; ++j) dst[j] = src[j];
    }
    {
      const int r = t >> 1, c32 = (t & 1) << 5;
      const float4* src = (const float4*)(Wq + (size_t)(c0 + r) * 1024 + h * 64 + c32);
      float4* dst = (float4*)&s_w[r * 68 + c32];
#pragma unroll
      for (int j = 0; j < 8; ++j) dst[j] = src[j];
    }
    __syncthreads();
    for (int cc = 0; cc < 128; ++cc) {
      const float a = s_hs[i * 132 + cc];
      const float4 w0 = *(const float4*)&s_w[cc * 68 + d0];
      const float4 w1 = *(const float4*)&s_w[cc * 68 + d0 + 4];
      acc8[0] += a * w0.x; acc8[1] += a * w0.y; acc8[2] += a * w0.z; acc8[3] += a * w0.w;
      acc8[4] += a * w1.x; acc8[5] += a * w1.y; acc8[6] += a * w1.z; acc8[7] += a * w1.w;
    }
  }
#pragma unroll
  for (int j = 0; j < 8; ++j) s_qr[i * 68 + d0 + j] = acc8[j];
  __syncthreads();

  // RoPE (query only), fold 1/sqrt(D)=0.125; int64/int32 position hedge
  unsigned oddor = 0;
  for (int j = 1; j < 256; j += 2) oddor |= (unsigned)pos[j];
  const int idx = b * 32 + i;
  const int p   = (oddor == 0) ? pos[2 * idx] : pos[idx];
  const float pf = (float)p;
  float qr8[8];
#pragma unroll
  for (int j = 0; j < 8; ++j) {
    const int d = d0 + j;
    const int f = d & 31;
    const float inv = powf(10000.0f, -(float)f * (1.0f / 32.0f));
    const float ang = pf * inv;
    float sn, cs; sincosf(ang, &sn, &cs);
    const float x  = s_qr[i * 68 + d];
    const float xr = (d < 32) ? -s_qr[i * 68 + d + 32] : s_qr[i * 68 + d - 32];
    qr8[j] = (x * cs + xr * sn) * 0.125f;
  }
  __syncthreads();
#pragma unroll
  for (int j = 0; j < 8; ++j) s_qr[i * 68 + d0 + j] = qr8[j];

  const int cb = t & 7;
  for (int c0 = 0; c0 < 1024; c0 += 128) {
    __syncthreads();
    {
      const int r = t >> 1, c32 = (t & 1) << 5;
      const float4* src = (const float4*)(Wk + (size_t)(c0 + r) * 1024 + h * 64 + c32);
      float4* dst = (float4*)&s_w[r * 68 + c32];
#pragma unroll
      for (int j = 0; j < 8; ++j) dst[j] = src[j];
    }
    __syncthreads();
    float acc16[16];
#pragma unroll
    for (int u = 0; u < 16; ++u) acc16[u] = 0.f;
    for (int d4 = 0; d4 < 16; ++d4) {
      const float4 q4 = *(const float4*)&s_qr[i * 68 + (d4 << 2)];
#pragma unroll
      for (int u = 0; u < 16; ++u) {
        const float4 w4 = *(const float4*)&s_w[(cb + (u << 3)) * 68 + (d4 << 2)];
        acc16[u] += q4.x * w4.x + q4.y * w4.y + q4.z * w4.z + q4.w * w4.w;
      }
    }
    ushort* dst = qk + ((size_t)b * 512 + h * 32 + i) * 1024 + c0 + cb;
#pragma unroll
    for (int u = 0; u < 16; ++u) dst[u << 3] = f2b(acc16[u]);
  }
}

// ---------------------------------------------------------------------------
// G1: scores = qk @ X^T. A = qk natural [z][512][1024] (swizzle in global
// addressing); B = Xp1 packed (linear staging). C written in packed-swizzled
// layout Sc[z][mt][ki(128)][r][p][e] + per-row (max,sumexp) partial stats
// computed from bf16-ROUNDED scores (self-consistent with stored values).
// grid (8 z, 32 nt, 4 mt), 256 thr.
// ---------------------------------------------------------------------------
__global__ __launch_bounds__(256) void gemm1(
    const ushort* __restrict__ qk, const ushort* __restrict__ Xp1,
    ushort* __restrict__ Sc, float2* __restrict__ pstat) {
  __shared__ alignas(16) ushort sA[4096];
  __shared__ alignas(16) ushort sB[4096];
  __shared__ float sMx[256], sSm[256];
  const int z = blockIdx.x, nty = blockIdx.y, mt = blockIdx.z;
  const int tid = threadIdx.x;
  const int wave = tid >> 6, lane = tid & 63;
  const int wm = wave >> 1, wn = wave & 1;
  const int fr = lane & 15, fq = lane >> 4;
  const int sfr = swz(fr);
  const int srow = lane >> 2;
  const int lc   = (lane & 3) ^ swz(srow);

  const ushort* Ab = qk + ((size_t)z * 512 + mt * 128) * 1024;
  const ushort* Bb = Xp1 + ((size_t)(z * 32 + nty) * 32) * 4096;

  f32x4 acc[4][4];
#pragma unroll
  for (int a = 0; a < 4; ++a)
#pragma unroll
    for (int c = 0; c < 4; ++c) acc[a][c] = (f32x4){0.f, 0.f, 0.f, 0.f};

  for (int it = 0; it < 32; ++it) {
    const int k0 = it << 5;
    const ushort* Bc = Bb + (size_t)it * 4096 + wave * 1024;
#pragma unroll
    for (int seg = 0; seg < 2; ++seg) {
      gload16(Bc + seg * 512 + lane * 8, &sB[wave * 1024 + seg * 512]);
      const int row = wave * 32 + seg * 16 + srow;
      gload16(Ab + (size_t)row * 1024 + k0 + lc * 8, &sA[wave * 1024 + seg * 512]);
    }
    __syncthreads();
    bf16x8 aF[4], bF[4];
#pragma unroll
    for (int u = 0; u < 4; ++u) {
      aF[u] = *(const bf16x8*)&sA[((wm << 6) + (u << 4) + fr) * 32 + ((fq ^ sfr) << 3)];
      bF[u] = *(const bf16x8*)&sB[((wn << 6) + (u << 4) + fr) * 32 + ((fq ^ sfr) << 3)];
    }
#pragma unroll
    for (int mi = 0; mi < 4; ++mi)
#pragma unroll
      for (int nt = 0; nt < 4; ++nt)
        acc[mi][nt] = __builtin_amdgcn_mfma_f32_16x16x32_bf16(
            aF[mi], bF[nt], acc[mi][nt], 0, 0, 0);
    __syncthreads();
  }

  // epilogue: write packed scores (bf16) and round acc for stats
  ushort* ScB = Sc + (size_t)(z * 4 + mt) * 524288;
#pragma unroll
  for (int mi = 0; mi < 4; ++mi)
#pragma unroll
    for (int nt = 0; nt < 4; ++nt)
#pragma unroll
      for (int r = 0; r < 4; ++r) {
        const int row = (wm << 6) + (mi << 4) + (fq << 2) + r;
        const int col = (wn << 6) + (nt << 4) + fr;
        const int ki  = (nty << 2) + (col >> 5);
        const int p   = ((col >> 3) & 3) ^ r ^ fq;
        const ushort hb = f2b(acc[mi][nt][r]);
        ScB[(size_t)ki * 4096 + row * 32 + p * 8 + (fr & 7)] = hb;
        acc[mi][nt][r] = b2f(hb);
      }

  // per-row stats over this block's 128 cols (two wn-halves via LDS)
#pragma unroll
  for (int mi = 0; mi < 4; ++mi)
#pragma unroll
    for (int r = 0; r < 4; ++r) {
      float m4 = fmaxf(fmaxf(acc[mi][0][r], acc[mi][1][r]),
                       fmaxf(acc[mi][2][r], acc[mi][3][r]));
#pragma unroll
      for (int o = 1; o < 16; o <<= 1) m4 = fmaxf(m4, __shfl_xor(m4, o));
      float s4 = __expf(acc[mi][0][r] - m4) + __expf(acc[mi][1][r] - m4) +
                 __expf(acc[mi][2][r] - m4) + __expf(acc[mi][3][r] - m4);
#pragma unroll
      for (int o = 1; o < 16; o <<= 1) s4 += __shfl_xor(s4, o);
      if (fr == 0) {
        const int row = (wm << 6) + (mi << 4) + (fq << 2) + r;
        sMx[row * 2 + wn] = m4;
        sSm[row * 2 + wn] = s4;
      }
    }
  __syncthreads();
  if (tid < 128) {
    const float m0 = sMx[tid * 2], m1 = sMx[tid * 2 + 1];
    const float M = fmaxf(m0, m1);
    const float S = sSm[tid * 2] * __expf(m0 - M) + sSm[tid * 2 + 1] * __expf(m1 - M);
    pstat[((size_t)(z * 512 + mt * 128 + tid)) * 32 + nty] = make_float2(M, S);
  }
}

// ---------------------------------------------------------------------------
// combine per-row stats: 4096 rows x 32 partials -> (M, 1/S). grid 16x256.
// ---------------------------------------------------------------------------
__global__ __launch_bounds__(256) void combine_stats(
    const float2* __restrict__ pstat, float2* __restrict__ stats2) {
  const int g = blockIdx.x * 256 + threadIdx.x;
  const float2* p = pstat + (size_t)g * 32;
  float M = -1e30f;
#pragma unroll
  for (int i = 0; i < 32; ++i) M = fmaxf(M, p[i].x);
  float S = 0.f;
#pragma unroll
  for (int i = 0; i < 32; ++i) S += p[i].y * __expf(p[i].x - M);
  stats2[g] = make_float2(M, 1.0f / S);
}

// ---------------------------------------------------------------------------
// apply softmax in place on packed scores. 16B per thread. grid 8192x256.
// ---------------------------------------------------------------------------
__global__ __launch_bounds__(256) void softmax_apply(
    ushort* __restrict__ Sc, const float2* __restrict__ stats2) {
  const size_t idx = (size_t)blockIdx.x * 256 + threadIdx.x;   // < 2^21
  const int row = (int)((idx >> 16) * 128 + ((idx >> 2) & 127));
  const float2 st = stats2[row];
  uint4 v = *(uint4*)(Sc + idx * 8);
  float x0, x1, x2, x3, x4, x5, x6, x7;
  unpack2(v.x, x0, x1); unpack2(v.y, x2, x3);
  unpack2(v.z, x4, x5); unpack2(v.w, x6, x7);
  v.x = packb(__expf(x0 - st.x) * st.y, __expf(x1 - st.x) * st.y);
  v.y = packb(__expf(x2 - st.x) * st.y, __expf(x3 - st.x) * st.y);
  v.z = packb(__expf(x4 - st.x) * st.y, __expf(x5 - st.x) * st.y);
  v.w = packb(__expf(x6 - st.x) * st.y, __expf(x7 - st.x) * st.y);
  *(uint4*)(Sc + idx * 8) = v;
}

// ---------------------------------------------------------------------------
// G2: ctx partials = attn @ X, K-split x4. A = Sc packed (linear staging),
// B = Xp2 packed. P[ks][z][512][1024] fp32 disjoint writes.
// grid (8 z, 8 nt, 16 (ks*4+mt)), 256 thr.
// ---------------------------------------------------------------------------
__global__ __launch_bounds__(256) void gemm2(
    const ushort* __restrict__ Sc, const ushort* __restrict__ Xp2,
    float* __restrict__ P) {
  __shared__ alignas(16) ushort sA[4096];
  __shared__ alignas(16) ushort sB[4096];
  const int z = blockIdx.x, nty = blockIdx.y;
  const int mt = blockIdx.z & 3, ks = blockIdx.z >> 2;
  const int tid = threadIdx.x;
  const int wave = tid >> 6, lane = tid & 63;
  const int wm = wave >> 1, wn = wave & 1;
  const int fr = lane & 15, fq = lane >> 4;
  const int sfr = swz(fr);

  const ushort* Ab = Sc + (size_t)(z * 4 + mt) * 524288 + (size_t)(ks * 32) * 4096;
  const ushort* Bb = Xp2 + ((size_t)(z * 8 + nty) * 128 + ks * 32) * 4096;

  f32x4 acc[4][4];
#pragma unroll
  for (int a = 0; a < 4; ++a)
#pragma unroll
    for (int c = 0; c < 4; ++c) acc[a][c] = (f32x4){0.f, 0.f, 0.f, 0.f};

  for (int it = 0; it < 32; ++it) {
    const ushort* Ac = Ab + (size_t)it * 4096 + wave * 1024;
    const ushort* Bc = Bb + (size_t)it * 4096 + wave * 1024;
#pragma unroll
    for (int seg = 0; seg < 2; ++seg) {
      gload16(Bc + seg * 512 + lane * 8, &sB[wave * 1024 + seg * 512]);
      gload16(Ac + seg * 512 + lane * 8, &sA[wave * 1024 + seg * 512]);
    }
    __syncthreads();
    bf16x8 aF[4], bF[4];
#pragma unroll
    for (int u = 0; u < 4; ++u) {
      aF[u] = *(const bf16x8*)&sA[((wm << 6) + (u << 4) + fr) * 32 + ((fq ^ sfr) << 3)];
      bF[u] = *(const bf16x8*)&sB[((wn << 6) + (u << 4) + fr) * 32 + ((fq ^ sfr) << 3)];
    }
#pragma unroll
    for (int mi = 0; mi < 4; ++mi)
#pragma unroll
      for (int nt = 0; nt < 4; ++nt)
        acc[mi][nt] = __builtin_amdgcn_mfma_f32_16x16x32_bf16(
            aF[mi], bF[nt], acc[mi][nt], 0, 0, 0);
    __syncthreads();
  }

  float* Pb = P + (((size_t)(ks * 8 + z) * 512) + mt * 128) * 1024 + nty * 128;
#pragma unroll
  for (int mi = 0; mi < 4; ++mi)
#pragma unroll
    for (int nt = 0; nt < 4; ++nt)
#pragma unroll
      for (int r = 0; r < 4; ++r) {
        const int row = (wm << 6) + (mi << 4) + (fq << 2) + r;
        const int col = (wn << 6) + (nt << 4) + fr;
        Pb[(size_t)row * 1024 + col] = acc[mi][nt][r];
      }
}

// ---------------------------------------------------------------------------
// K6a: tmp2[b*32+i][h*64+d] = sum_c (sum_ks P[ks][b][h*32+i][c]) * Wv[c][h*64+d]
// grid 128 (b,h), 256 thr.
// ---------------------------------------------------------------------------
__global__ __launch_bounds__(256) void ctx_wv(
    const float* __restrict__ P, const float* __restrict__ Wv,
    float* __restrict__ tmp2) {
  const int b = blockIdx.x >> 4, h = blockIdx.x & 15;
  const int t = threadIdx.x;
  __shared__ float s_a[32 * 132];
  __shared__ float s_w[128 * 68];
  const int i = t >> 3, d0 = (t & 7) << 3;
  float acc8[8];
#pragma unroll
  for (int j = 0; j < 8; ++j) acc8[j] = 0.f;

  for (int c0 = 0; c0 < 1024; c0 += 128) {
    __syncthreads();
    {
      const int r = t >> 3, cc = (t & 7) << 4;
      float4 v[4];
#pragma unroll
      for (int q = 0; q < 4; ++q) v[q] = (float4){0.f, 0.f, 0.f, 0.f};
#pragma unroll
      for (int ksi = 0; ksi < 4; ++ksi) {
        const float4* sp = (const float4*)(P +
            (((size_t)(ksi * 8 + b) * 512 + h * 32 + r) * 1024) + c0 + cc);
#pragma unroll
        for (int q = 0; q < 4; ++q) {
          const float4 u = sp[q];
          v[q].x += u.x; v[q].y += u.y; v[q].z += u.z; v[q].w += u.w;
        }
      }
      float4* dst = (float4*)&s_a[r * 132 + cc];
#pragma unroll
      for (int q = 0; q < 4; ++q) dst[q] = v[q];
    }
    {
      const int r = t >> 1, c32 = (t & 1) << 5;
      const float4* src = (const float4*)(Wv + (size_t)(c0 + r) * 1024 + h * 64 + c32);
      float4* dst = (float4*)&s_w[r * 68 + c32];
#pragma unroll
      for (int j = 0; j < 8; ++j) dst[j] = src[j];
    }
    __syncthreads();
    for (int cc = 0; cc < 128; ++cc) {
      const float a = s_a[i * 132 + cc];
      const float4 w0 = *(const float4*)&s_w[cc * 68 + d0];
      const float4 w1 = *(const float4*)&s_w[cc * 68 + d0 + 4];
      acc8[0] += a * w0.x; acc8[1] += a * w0.y; acc8[2] += a * w0.z; acc8[3] += a * w0.w;
      acc8[4] += a * w1.x; acc8[5] += a * w1.y; acc8[6] += a * w1.z; acc8[7] += a * w1.w;
    }
  }
  float* dst = tmp2 + ((size_t)b * 32 + i) * 1024 + h * 64 + d0;
#pragma unroll
  for (int j = 0; j < 8; ++j) dst[j] = acc8[j];
}

// ---------------------------------------------------------------------------
// K6b: out = tmp2 @ Wo : [256,1024]@[1024,1024], fp32.
// ---------------------------------------------------------------------------
__global__ __launch_bounds__(256) void out_proj(
    const float* __restrict__ A, const float* __restrict__ Wo,
    float* __restrict__ out) {
  const int mt = blockIdx.x >> 4, nt = blockIdx.x & 15;
  const int m0 = mt << 4, n0 = nt << 6;
  const int t  = threadIdx.x;
  __shared__ float sA[16 * 68];
  __shared__ float sW[64 * 68];
  const int n = t & 63, mg = t >> 6;
  float acc[4] = {0.f, 0.f, 0.f, 0.f};

  for (int k0 = 0; k0 < 1024; k0 += 64) {
    __syncthreads();
    {
      const int r = t >> 4, c = (t & 15) << 2;
      *(float4*)&sA[r * 68 + c] = *(const float4*)&A[(size_t)(m0 + r) * 1024 + k0 + c];
    }
    {
      const int r = t >> 2, c = (t & 3) << 4;
      const float4* s = (const float4*)&Wo[(size_t)(k0 + r) * 1024 + n0 + c];
      float4* d = (float4*)&sW[r * 68 + c];
      d[0] = s[0]; d[1] = s[1]; d[2] = s[2]; d[3] = s[3];
    }
    __syncthreads();
    for (int kk = 0; kk < 64; ++kk) {
      const float w = sW[kk * 68 + n];
#pragma unroll
      for (int r = 0; r < 4; ++r) acc[r] += sA[((mg << 2) + r) * 68 + kk] * w;
    }
  }
#pragma unroll
  for (int r = 0; r < 4; ++r)
    out[(size_t)(m0 + (mg << 2) + r) * 1024 + n0 + n] = acc[r];
}

// ---------------------------------------------------------------------------
extern "C" void kernel_launch(void* const* d_in, const int* in_sizes, int n_in,
                              void* d_out, int out_size, void* d_ws, size_t ws_size,
                              hipStream_t stream) {
  const float* hs  = (const float*)d_in[0];
  const float* enc = (const float*)d_in[1];
  const int*   pos = (const int*)d_in[2];
  const float* Wq  = (const float*)d_in[3];
  const float* Wk  = (const float*)d_in[4];
  const float* Wv  = (const float*)d_in[5];
  const float* Wo  = (const float*)d_in[6];
  float* out = (float*)d_out;

  char* w = (char*)d_ws;
  ushort* Xp1  = (ushort*)w;                 // 67,108,864 B (gemm1 B)
  float*  P    = (float*)w;                  // ALIAS: ctx partials (after gemm1 done)
  w += (size_t)67108864;
  ushort* Xp2  = (ushort*)w; w += (size_t)67108864;   // gemm2 B
  ushort* qk   = (ushort*)w; w += (size_t)8388608;    // [8][512][1024] bf16
  ushort* Sc   = (ushort*)w; w += (size_t)33554432;   // packed scores/attn
  float2* pstat  = (float2*)w; w += (size_t)1048576;  // [4096 rows][32] (M,S)
  float2* stats2 = (float2*)w; w += (size_t)32768;    // [4096 rows] (M,1/S)
  float*  tmp2 = (float*)w;  w += (size_t)1048576;    // [256][1024] fp32

  pack_x<<<dim3(16, 32, 8), 256, 0, stream>>>(enc, Xp1, Xp2);
  qk_proj<<<128, 256, 0, stream>>>(hs, Wq, Wk, pos, qk);
  gemm1<<<dim3(8, 32, 4), 256, 0, stream>>>(qk, Xp1, Sc, pstat);
  combine_stats<<<16, 256, 0, stream>>>(pstat, stats2);
  softmax_apply<<<8192, 256, 0, stream>>>(Sc, stats2);
  gemm2<<<dim3(8, 8, 16), 256, 0, stream>>>(Sc, Xp2, P);
  ctx_wv<<<128, 256, 0, stream>>>(P, Wv, tmp2);
  out_proj<<<256, 256, 0, stream>>>(tmp2, Wo, out);
}

// Round 3
// 468.961 us; speedup vs baseline: 1.2191x; 1.1817x over previous
//
#include <hip/hip_runtime.h>

// ---------------------------------------------------------------------------
// R3: replace the three VALU mini-GEMM kernels (qk_proj 99us, ctx_wv,
// out_proj — all MfmaUtil=0, occupancy ~5%) with MFMA kernels at proper
// parallelism. gemm1/gemm2/pack_x/softmax pipeline unchanged from R2.
// ---------------------------------------------------------------------------

typedef float  f32x4  __attribute__((ext_vector_type(4)));
typedef __bf16 bf16x8 __attribute__((ext_vector_type(8)));

__device__ __forceinline__ ushort f2b(float x) {
  union { float f; unsigned u; } v; v.f = x;
  unsigned r = (v.u + 0x7fffu + ((v.u >> 16) & 1u)) >> 16;
  return (ushort)r;
}
__device__ __forceinline__ float b2f(ushort h) {
  union { unsigned u; float f; } v; v.u = ((unsigned)h) << 16; return v.f;
}
__device__ __forceinline__ void unpack2(unsigned v, float& lo, float& hi) {
  union { unsigned u; float f; } a, b;
  a.u = v << 16; b.u = v & 0xffff0000u;
  lo = a.f; hi = b.f;
}
__device__ __forceinline__ unsigned packb(float a, float b) {
  return (unsigned)f2b(a) | ((unsigned)f2b(b) << 16);
}
__device__ __forceinline__ int swz(int r) { return (r & 3) ^ ((r >> 2) & 3); }

__device__ __forceinline__ void gload16(const void* g, void* l) {
  __builtin_amdgcn_global_load_lds(
      (const __attribute__((address_space(1))) void*)g,
      (__attribute__((address_space(3))) void*)l, 16, 0, 0);
}

// ---------------------------------------------------------------------------
// K1: pack X (fp32 [8][4096][1024]) into Xp1 (gemm1 B) and Xp2 (gemm2 B).
// (unchanged from R2)
// ---------------------------------------------------------------------------
__global__ __launch_bounds__(256) void pack_x(
    const float* __restrict__ X, ushort* __restrict__ Xp1, ushort* __restrict__ Xp2) {
  const int z = blockIdx.z, jb = blockIdx.y, cb = blockIdx.x;
  const int t = threadIdx.x;
  __shared__ ushort sT[128 * 72];

#pragma unroll
  for (int rep = 0; rep < 2; ++rep) {
    const int j  = rep * 64 + (t >> 2);
    const int c0 = (t & 3) << 4;
    const float4* src = (const float4*)(X + ((size_t)z * 4096 + jb * 128 + j) * 1024 + cb * 64 + c0);
#pragma unroll
    for (int q = 0; q < 4; ++q) {
      const float4 v = src[q];
      ushort4 w; w.x = f2b(v.x); w.y = f2b(v.y); w.z = f2b(v.z); w.w = f2b(v.w);
      *(ushort4*)&sT[j * 72 + c0 + q * 4] = w;
    }
  }
  __syncthreads();

  ushort* o1 = Xp1 + ((size_t)(z * 32 + jb) * 32 + cb * 2) * 4096;
#pragma unroll
  for (int q = 0; q < 4; ++q) {
    const int kih = q >> 1;
    const int r   = ((q & 1) << 6) + (t >> 2);
    const int p   = t & 3;
    const int lc  = p ^ swz(r);
    const uint4 v = *(const uint4*)&sT[r * 72 + kih * 32 + lc * 8];
    *(uint4*)&o1[(size_t)kih * 4096 + ((size_t)(q & 1) << 11) + (size_t)t * 8] = v;
  }

  ushort* o2 = Xp2 + (((size_t)(z * 8 + (cb >> 1)) * 128 + jb * 4) * 4096) + ((size_t)(cb & 1) << 11);
#pragma unroll
  for (int q = 0; q < 4; ++q) {
    const int cl = t >> 2;
    const int p2 = t & 3;
    const int lj = p2 ^ swz(cl);
    union { ushort u[8]; uint4 v; } pk;
#pragma unroll
    for (int jj = 0; jj < 8; ++jj) pk.u[jj] = sT[(q * 32 + lj * 8 + jj) * 72 + cl];
    *(uint4*)&o2[(size_t)q * 4096 + (size_t)t * 8] = pk.v;
  }
}

// ---------------------------------------------------------------------------
// pack_w: cast 4 weights to bf16. wsel 0:Wq->WqT (transposed [out][in]),
// 1:Wk->Wkb (natural [in][out]), 2:Wv->WvT, 3:Wo->WoT. grid (16,16,4).
// ---------------------------------------------------------------------------
__global__ __launch_bounds__(256) void pack_w(
    const float* __restrict__ Wq, const float* __restrict__ Wk,
    const float* __restrict__ Wv, const float* __restrict__ Wo,
    ushort* __restrict__ WqT, ushort* __restrict__ Wkb,
    ushort* __restrict__ WvT, ushort* __restrict__ WoT) {
  const int wsel = blockIdx.z;
  const float* src = (wsel == 0) ? Wq : (wsel == 1) ? Wk : (wsel == 2) ? Wv : Wo;
  const int row0 = blockIdx.y << 6, col0 = blockIdx.x << 6;
  const int t = threadIdx.x;
  __shared__ ushort sT[64 * 72];
  const int r = t >> 2, c0 = (t & 3) << 4;

  union { ushort u[16]; uint4 v[2]; } pk;
  const float4* s4 = (const float4*)(src + (size_t)(row0 + r) * 1024 + col0 + c0);
#pragma unroll
  for (int q = 0; q < 4; ++q) {
    const float4 v = s4[q];
    pk.u[q*4+0] = f2b(v.x); pk.u[q*4+1] = f2b(v.y);
    pk.u[q*4+2] = f2b(v.z); pk.u[q*4+3] = f2b(v.w);
  }
  if (wsel == 1) {
    ushort* dst = Wkb + (size_t)(row0 + r) * 1024 + col0 + c0;
    *(uint4*)dst = pk.v[0];
    *(uint4*)(dst + 8) = pk.v[1];
  } else {
#pragma unroll
    for (int q = 0; q < 16; ++q) sT[r * 72 + c0 + q] = pk.u[q];
    __syncthreads();
    ushort* dst = (wsel == 0) ? WqT : (wsel == 2) ? WvT : WoT;
    union { ushort u[16]; uint4 v[2]; } o;
#pragma unroll
    for (int q = 0; q < 16; ++q) o.u[q] = sT[(c0 + q) * 72 + r];
    ushort* d = dst + (size_t)(col0 + r) * 1024 + row0 + c0;
    *(uint4*)d = o.v[0];
    *(uint4*)(d + 8) = o.v[1];
  }
}

// ---------------------------------------------------------------------------
// qrope_gemm: q = hs @ Wq, M=256 N=1024 K=1024, K-split x4 -> qP fp32.
// 128x128 tile, BK=32, fp32 A cast to bf16 in staging. grid (8,2,4).
// ---------------------------------------------------------------------------
__global__ __launch_bounds__(256) void qrope_gemm(
    const float* __restrict__ hs, const ushort* __restrict__ WqT,
    float* __restrict__ qP) {
  __shared__ alignas(16) ushort sA[128 * 40];
  __shared__ alignas(16) ushort sB[128 * 40];
  const int nt = blockIdx.x, mt = blockIdx.y, ks = blockIdx.z;
  const int m0 = mt << 7, n0 = nt << 7, kb = ks << 8;
  const int t = threadIdx.x;
  const int wave = t >> 6, lane = t & 63;
  const int wm = wave >> 1, wn = wave & 1;
  const int fr = lane & 15, fq = lane >> 4;
  const int r = t >> 1, sg = (t & 1) << 4;

  f32x4 acc[4][4];
#pragma unroll
  for (int a = 0; a < 4; ++a)
#pragma unroll
    for (int c = 0; c < 4; ++c) acc[a][c] = (f32x4){0.f, 0.f, 0.f, 0.f};

  for (int it = 0; it < 8; ++it) {
    const int k0 = kb + (it << 5);
    {
      const float4* s4 = (const float4*)(hs + (size_t)(m0 + r) * 1024 + k0 + sg);
      union { ushort u[16]; uint4 v[2]; } pk;
#pragma unroll
      for (int q = 0; q < 4; ++q) {
        const float4 v = s4[q];
        pk.u[q*4+0] = f2b(v.x); pk.u[q*4+1] = f2b(v.y);
        pk.u[q*4+2] = f2b(v.z); pk.u[q*4+3] = f2b(v.w);
      }
      *(uint4*)&sA[r * 40 + sg]     = pk.v[0];
      *(uint4*)&sA[r * 40 + sg + 8] = pk.v[1];
    }
    {
      const uint4* s4 = (const uint4*)(WqT + (size_t)(n0 + r) * 1024 + k0 + sg);
      *(uint4*)&sB[r * 40 + sg]     = s4[0];
      *(uint4*)&sB[r * 40 + sg + 8] = s4[1];
    }
    __syncthreads();
    bf16x8 aF[4], bF[4];
#pragma unroll
    for (int u = 0; u < 4; ++u) {
      aF[u] = *(const bf16x8*)&sA[((wm << 6) + (u << 4) + fr) * 40 + (fq << 3)];
      bF[u] = *(const bf16x8*)&sB[((wn << 6) + (u << 4) + fr) * 40 + (fq << 3)];
    }
#pragma unroll
    for (int mi = 0; mi < 4; ++mi)
#pragma unroll
      for (int ni = 0; ni < 4; ++ni)
        acc[mi][ni] = __builtin_amdgcn_mfma_f32_16x16x32_bf16(
            aF[mi], bF[ni], acc[mi][ni], 0, 0, 0);
    __syncthreads();
  }
  float* dst = qP + (size_t)ks * 262144;
#pragma unroll
  for (int mi = 0; mi < 4; ++mi)
#pragma unroll
    for (int ni = 0; ni < 4; ++ni)
#pragma unroll
      for (int rr = 0; rr < 4; ++rr) {
        const int row = m0 + (wm << 6) + (mi << 4) + (fq << 2) + rr;
        const int col = n0 + (wn << 6) + (ni << 4) + fr;
        dst[(size_t)row * 1024 + col] = acc[mi][ni][rr];
      }
}

// ---------------------------------------------------------------------------
// rope_apply: qr = bf16( RoPE(sum_ks qP) * 0.125 ). Each thread owns an
// 8-col chunk in the first half of a head and its +32 partner. 64 blocks.
// ---------------------------------------------------------------------------
__global__ __launch_bounds__(256) void rope_apply(
    const float* __restrict__ qP, const int* __restrict__ pos,
    ushort* __restrict__ qr) {
  const int idx = blockIdx.x * 256 + threadIdx.x;   // < 16384
  const int m = idx >> 6;
  const int u = idx & 63;
  const int h = u >> 2;
  const int c8 = (u & 3) << 3;       // d in [0,32)
  const int colx = h * 64 + c8;
  const int coly = colx + 32;

  float x[8], y[8];
#pragma unroll
  for (int j = 0; j < 8; ++j) { x[j] = 0.f; y[j] = 0.f; }
#pragma unroll
  for (int p = 0; p < 4; ++p) {
    const float* base = qP + (size_t)p * 262144 + (size_t)m * 1024;
    const float4 a0 = *(const float4*)(base + colx);
    const float4 a1 = *(const float4*)(base + colx + 4);
    const float4 b0 = *(const float4*)(base + coly);
    const float4 b1 = *(const float4*)(base + coly + 4);
    x[0]+=a0.x; x[1]+=a0.y; x[2]+=a0.z; x[3]+=a0.w;
    x[4]+=a1.x; x[5]+=a1.y; x[6]+=a1.z; x[7]+=a1.w;
    y[0]+=b0.x; y[1]+=b0.y; y[2]+=b0.z; y[3]+=b0.w;
    y[4]+=b1.x; y[5]+=b1.y; y[6]+=b1.z; y[7]+=b1.w;
  }

  // int64/int32 position hedge (odd 32-bit slots all zero <=> int64)
  unsigned oddor = 0;
  for (int j = 1; j < 256; j += 2) oddor |= (unsigned)pos[j];
  const int p = (oddor == 0) ? pos[2 * m] : pos[m];
  const float pf = (float)p;

  union { ushort u16[8]; uint4 v; } ox, oy;
#pragma unroll
  for (int j = 0; j < 8; ++j) {
    const int f = c8 + j;
    const float inv = powf(10000.0f, -(float)f * (1.0f / 32.0f));
    float sn, cs; sincosf(pf * inv, &sn, &cs);
    ox.u16[j] = f2b((x[j] * cs - y[j] * sn) * 0.125f);
    oy.u16[j] = f2b((y[j] * cs + x[j] * sn) * 0.125f);
  }
  *(uint4*)(qr + (size_t)m * 1024 + colx) = ox.v;
  *(uint4*)(qr + (size_t)m * 1024 + coly) = oy.v;
}

// ---------------------------------------------------------------------------
// qk_gemm: per (b,h): qk[b, h*32+i, c] = sum_d qr[b*32+i, h*64+d]*Wkb[c, h*64+d]
// M=32 N=256 K=64 per block. grid (4 nc, 16 h, 8 b) = 512 blocks.
// ---------------------------------------------------------------------------
__global__ __launch_bounds__(256) void qk_gemm(
    const ushort* __restrict__ qr, const ushort* __restrict__ Wkb,
    ushort* __restrict__ qk) {
  __shared__ alignas(16) ushort sA[32 * 72];
  __shared__ alignas(16) ushort sB[256 * 72];
  const int nc = blockIdx.x, h = blockIdx.y, b = blockIdx.z;
  const int t = threadIdx.x;
  {
    const int i = t >> 3, seg = (t & 7) << 3;
    *(uint4*)&sA[i * 72 + seg] =
        *(const uint4*)(qr + (size_t)(b * 32 + i) * 1024 + h * 64 + seg);
  }
#pragma unroll
  for (int p = 0; p < 8; ++p) {
    const int rr = (t >> 3) + p * 32, seg = (t & 7) << 3;
    *(uint4*)&sB[rr * 72 + seg] =
        *(const uint4*)(Wkb + (size_t)(nc * 256 + rr) * 1024 + h * 64 + seg);
  }
  __syncthreads();

  const int wave = t >> 6, lane = t & 63;
  const int fr = lane & 15, fq = lane >> 4;
  f32x4 acc[2][4];
#pragma unroll
  for (int a = 0; a < 2; ++a)
#pragma unroll
    for (int c = 0; c < 4; ++c) acc[a][c] = (f32x4){0.f, 0.f, 0.f, 0.f};

#pragma unroll
  for (int ki = 0; ki < 2; ++ki) {
    bf16x8 aF[2], bF[4];
#pragma unroll
    for (int mi = 0; mi < 2; ++mi)
      aF[mi] = *(const bf16x8*)&sA[((mi << 4) + fr) * 72 + (ki << 5) + (fq << 3)];
#pragma unroll
    for (int ni = 0; ni < 4; ++ni)
      bF[ni] = *(const bf16x8*)&sB[((wave << 6) + (ni << 4) + fr) * 72 + (ki << 5) + (fq << 3)];
#pragma unroll
    for (int mi = 0; mi < 2; ++mi)
#pragma unroll
      for (int ni = 0; ni < 4; ++ni)
        acc[mi][ni] = __builtin_amdgcn_mfma_f32_16x16x32_bf16(
            aF[mi], bF[ni], acc[mi][ni], 0, 0, 0);
  }
#pragma unroll
  for (int mi = 0; mi < 2; ++mi)
#pragma unroll
    for (int ni = 0; ni < 4; ++ni)
#pragma unroll
      for (int rr = 0; rr < 4; ++rr) {
        const int row = h * 32 + (mi << 4) + (fq << 2) + rr;
        const int col = nc * 256 + (wave << 6) + (ni << 4) + fr;
        qk[((size_t)b * 512 + row) * 1024 + col] = f2b(acc[mi][ni][rr]);
      }
}

// ---------------------------------------------------------------------------
// G1: scores = qk @ X^T (unchanged from R2)
// ---------------------------------------------------------------------------
__global__ __launch_bounds__(256) void gemm1(
    const ushort* __restrict__ qk, const ushort* __restrict__ Xp1,
    ushort* __restrict__ Sc, float2* __restrict__ pstat) {
  __shared__ alignas(16) ushort sA[4096];
  __shared__ alignas(16) ushort sB[4096];
  __shared__ float sMx[256], sSm[256];
  const int z = blockIdx.x, nty = blockIdx.y, mt = blockIdx.z;
  const int tid = threadIdx.x;
  const int wave = tid >> 6, lane = tid & 63;
  const int wm = wave >> 1, wn = wave & 1;
  const int fr = lane & 15, fq = lane >> 4;
  const int sfr = swz(fr);
  const int srow = lane >> 2;
  const int lc   = (lane & 3) ^ swz(srow);

  const ushort* Ab = qk + ((size_t)z * 512 + mt * 128) * 1024;
  const ushort* Bb = Xp1 + ((size_t)(z * 32 + nty) * 32) * 4096;

  f32x4 acc[4][4];
#pragma unroll
  for (int a = 0; a < 4; ++a)
#pragma unroll
    for (int c = 0; c < 4; ++c) acc[a][c] = (f32x4){0.f, 0.f, 0.f, 0.f};

  for (int it = 0; it < 32; ++it) {
    const int k0 = it << 5;
    const ushort* Bc = Bb + (size_t)it * 4096 + wave * 1024;
#pragma unroll
    for (int seg = 0; seg < 2; ++seg) {
      gload16(Bc + seg * 512 + lane * 8, &sB[wave * 1024 + seg * 512]);
      const int row = wave * 32 + seg * 16 + srow;
      gload16(Ab + (size_t)row * 1024 + k0 + lc * 8, &sA[wave * 1024 + seg * 512]);
    }
    __syncthreads();
    bf16x8 aF[4], bF[4];
#pragma unroll
    for (int u = 0; u < 4; ++u) {
      aF[u] = *(const bf16x8*)&sA[((wm << 6) + (u << 4) + fr) * 32 + ((fq ^ sfr) << 3)];
      bF[u] = *(const bf16x8*)&sB[((wn << 6) + (u << 4) + fr) * 32 + ((fq ^ sfr) << 3)];
    }
#pragma unroll
    for (int mi = 0; mi < 4; ++mi)
#pragma unroll
      for (int nt = 0; nt < 4; ++nt)
        acc[mi][nt] = __builtin_amdgcn_mfma_f32_16x16x32_bf16(
            aF[mi], bF[nt], acc[mi][nt], 0, 0, 0);
    __syncthreads();
  }

  ushort* ScB = Sc + (size_t)(z * 4 + mt) * 524288;
#pragma unroll
  for (int mi = 0; mi < 4; ++mi)
#pragma unroll
    for (int nt = 0; nt < 4; ++nt)
#pragma unroll
      for (int r = 0; r < 4; ++r) {
        const int row = (wm << 6) + (mi << 4) + (fq << 2) + r;
        const int col = (wn << 6) + (nt << 4) + fr;
        const int ki  = (nty << 2) + (col >> 5);
        const int p   = ((col >> 3) & 3) ^ r ^ fq;
        const ushort hb = f2b(acc[mi][nt][r]);
        ScB[(size_t)ki * 4096 + row * 32 + p * 8 + (fr & 7)] = hb;
        acc[mi][nt][r] = b2f(hb);
      }

#pragma unroll
  for (int mi = 0; mi < 4; ++mi)
#pragma unroll
    for (int r = 0; r < 4; ++r) {
      float m4 = fmaxf(fmaxf(acc[mi][0][r], acc[mi][1][r]),
                       fmaxf(acc[mi][2][r], acc[mi][3][r]));
#pragma unroll
      for (int o = 1; o < 16; o <<= 1) m4 = fmaxf(m4, __shfl_xor(m4, o));
      float s4 = __expf(acc[mi][0][r] - m4) + __expf(acc[mi][1][r] - m4) +
                 __expf(acc[mi][2][r] - m4) + __expf(acc[mi][3][r] - m4);
#pragma unroll
      for (int o = 1; o < 16; o <<= 1) s4 += __shfl_xor(s4, o);
      if (fr == 0) {
        const int row = (wm << 6) + (mi << 4) + (fq << 2) + r;
        sMx[row * 2 + wn] = m4;
        sSm[row * 2 + wn] = s4;
      }
    }
  __syncthreads();
  if (tid < 128) {
    const float m0 = sMx[tid * 2], m1 = sMx[tid * 2 + 1];
    const float M = fmaxf(m0, m1);
    const float S = sSm[tid * 2] * __expf(m0 - M) + sSm[tid * 2 + 1] * __expf(m1 - M);
    pstat[((size_t)(z * 512 + mt * 128 + tid)) * 32 + nty] = make_float2(M, S);
  }
}

// ---------------------------------------------------------------------------
__global__ __launch_bounds__(256) void combine_stats(
    const float2* __restrict__ pstat, float2* __restrict__ stats2) {
  const int g = blockIdx.x * 256 + threadIdx.x;
  const float2* p = pstat + (size_t)g * 32;
  float M = -1e30f;
#pragma unroll
  for (int i = 0; i < 32; ++i) M = fmaxf(M, p[i].x);
  float S = 0.f;
#pragma unroll
  for (int i = 0; i < 32; ++i) S += p[i].y * __expf(p[i].x - M);
  stats2[g] = make_float2(M, 1.0f / S);
}

// ---------------------------------------------------------------------------
__global__ __launch_bounds__(256) void softmax_apply(
    ushort* __restrict__ Sc, const float2* __restrict__ stats2) {
  const size_t idx = (size_t)blockIdx.x * 256 + threadIdx.x;
  const int row = (int)((idx >> 16) * 128 + ((idx >> 2) & 127));
  const float2 st = stats2[row];
  uint4 v = *(uint4*)(Sc + idx * 8);
  float x0, x1, x2, x3, x4, x5, x6, x7;
  unpack2(v.x, x0, x1); unpack2(v.y, x2, x3);
  unpack2(v.z, x4, x5); unpack2(v.w, x6, x7);
  v.x = packb(__expf(x0 - st.x) * st.y, __expf(x1 - st.x) * st.y);
  v.y = packb(__expf(x2 - st.x) * st.y, __expf(x3 - st.x) * st.y);
  v.z = packb(__expf(x4 - st.x) * st.y, __expf(x5 - st.x) * st.y);
  v.w = packb(__expf(x6 - st.x) * st.y, __expf(x7 - st.x) * st.y);
  *(uint4*)(Sc + idx * 8) = v;
}

// ---------------------------------------------------------------------------
// G2: ctx partials = attn @ X (unchanged from R2)
// ---------------------------------------------------------------------------
__global__ __launch_bounds__(256) void gemm2(
    const ushort* __restrict__ Sc, const ushort* __restrict__ Xp2,
    float* __restrict__ P) {
  __shared__ alignas(16) ushort sA[4096];
  __shared__ alignas(16) ushort sB[4096];
  const int z = blockIdx.x, nty = blockIdx.y;
  const int mt = blockIdx.z & 3, ks = blockIdx.z >> 2;
  const int tid = threadIdx.x;
  const int wave = tid >> 6, lane = tid & 63;
  const int wm = wave >> 1, wn = wave & 1;
  const int fr = lane & 15, fq = lane >> 4;
  const int sfr = swz(fr);

  const ushort* Ab = Sc + (size_t)(z * 4 + mt) * 524288 + (size_t)(ks * 32) * 4096;
  const ushort* Bb = Xp2 + ((size_t)(z * 8 + nty) * 128 + ks * 32) * 4096;

  f32x4 acc[4][4];
#pragma unroll
  for (int a = 0; a < 4; ++a)
#pragma unroll
    for (int c = 0; c < 4; ++c) acc[a][c] = (f32x4){0.f, 0.f, 0.f, 0.f};

  for (int it = 0; it < 32; ++it) {
    const ushort* Ac = Ab + (size_t)it * 4096 + wave * 1024;
    const ushort* Bc = Bb + (size_t)it * 4096 + wave * 1024;
#pragma unroll
    for (int seg = 0; seg < 2; ++seg) {
      gload16(Bc + seg * 512 + lane * 8, &sB[wave * 1024 + seg * 512]);
      gload16(Ac + seg * 512 + lane * 8, &sA[wave * 1024 + seg * 512]);
    }
    __syncthreads();
    bf16x8 aF[4], bF[4];
#pragma unroll
    for (int u = 0; u < 4; ++u) {
      aF[u] = *(const bf16x8*)&sA[((wm << 6) + (u << 4) + fr) * 32 + ((fq ^ sfr) << 3)];
      bF[u] = *(const bf16x8*)&sB[((wn << 6) + (u << 4) + fr) * 32 + ((fq ^ sfr) << 3)];
    }
#pragma unroll
    for (int mi = 0; mi < 4; ++mi)
#pragma unroll
      for (int nt = 0; nt < 4; ++nt)
        acc[mi][nt] = __builtin_amdgcn_mfma_f32_16x16x32_bf16(
            aF[mi], bF[nt], acc[mi][nt], 0, 0, 0);
    __syncthreads();
  }

  float* Pb = P + (((size_t)(ks * 8 + z) * 512) + mt * 128) * 1024 + nty * 128;
#pragma unroll
  for (int mi = 0; mi < 4; ++mi)
#pragma unroll
    for (int nt = 0; nt < 4; ++nt)
#pragma unroll
      for (int r = 0; r < 4; ++r) {
        const int row = (wm << 6) + (mi << 4) + (fq << 2) + r;
        const int col = (wn << 6) + (nt << 4) + fr;
        Pb[(size_t)row * 1024 + col] = acc[mi][nt][r];
      }
}

// ---------------------------------------------------------------------------
// reduce4_bf16: dst[i] = bf16(sum_{p<4} src[p*partStride + i]), 8 elems/thread.
// ---------------------------------------------------------------------------
__global__ __launch_bounds__(256) void reduce4_bf16(
    const float* __restrict__ src, ushort* __restrict__ dst, long partStride) {
  const size_t i8 = ((size_t)blockIdx.x * 256 + threadIdx.x) * 8;
  float s[8];
#pragma unroll
  for (int j = 0; j < 8; ++j) s[j] = 0.f;
#pragma unroll
  for (int p = 0; p < 4; ++p) {
    const float4 a = *(const float4*)(src + (size_t)p * partStride + i8);
    const float4 b = *(const float4*)(src + (size_t)p * partStride + i8 + 4);
    s[0] += a.x; s[1] += a.y; s[2] += a.z; s[3] += a.w;
    s[4] += b.x; s[5] += b.y; s[6] += b.z; s[7] += b.w;
  }
  union { ushort u[8]; uint4 v; } o;
#pragma unroll
  for (int j = 0; j < 8; ++j) o.u[j] = f2b(s[j]);
  *(uint4*)(dst + i8) = o.v;
}

// ---------------------------------------------------------------------------
// ctxwv_gemm: per (b,h): tmp2[b*32+i, h*64+d] partial over K-window ks*256.
// M=32 N=64 K=256. grid (4 ks, 16 h, 8 b) = 512 blocks -> P2 fp32 [4][256][1024].
// ---------------------------------------------------------------------------
__global__ __launch_bounds__(256) void ctxwv_gemm(
    const ushort* __restrict__ ctx, const ushort* __restrict__ WvT,
    float* __restrict__ P2) {
  __shared__ alignas(16) ushort sA[32 * 264];
  __shared__ alignas(16) ushort sB[64 * 264];
  const int ks = blockIdx.x, h = blockIdx.y, b = blockIdx.z;
  const int kb = ks << 8;
  const int t = threadIdx.x;
#pragma unroll
  for (int p = 0; p < 4; ++p) {
    const int i = t >> 3, seg = ((t & 7) + p * 8) << 3;
    *(uint4*)&sA[i * 264 + seg] =
        *(const uint4*)(ctx + ((size_t)b * 512 + h * 32 + i) * 1024 + kb + seg);
  }
#pragma unroll
  for (int p = 0; p < 8; ++p) {
    const int rr = (t >> 3) + (p & 1) * 32;
    const int seg = ((t & 7) + (p >> 1) * 8) << 3;
    *(uint4*)&sB[rr * 264 + seg] =
        *(const uint4*)(WvT + (size_t)(h * 64 + rr) * 1024 + kb + seg);
  }
  __syncthreads();

  const int wave = t >> 6, lane = t & 63;
  const int fr = lane & 15, fq = lane >> 4;
  f32x4 acc[2];
  acc[0] = (f32x4){0.f, 0.f, 0.f, 0.f};
  acc[1] = (f32x4){0.f, 0.f, 0.f, 0.f};

#pragma unroll
  for (int ki = 0; ki < 8; ++ki) {
    bf16x8 bFr = *(const bf16x8*)&sB[((wave << 4) + fr) * 264 + (ki << 5) + (fq << 3)];
#pragma unroll
    for (int mi = 0; mi < 2; ++mi) {
      bf16x8 aF = *(const bf16x8*)&sA[((mi << 4) + fr) * 264 + (ki << 5) + (fq << 3)];
      acc[mi] = __builtin_amdgcn_mfma_f32_16x16x32_bf16(aF, bFr, acc[mi], 0, 0, 0);
    }
  }
  float* dst = P2 + (size_t)ks * 262144;
#pragma unroll
  for (int mi = 0; mi < 2; ++mi)
#pragma unroll
    for (int rr = 0; rr < 4; ++rr) {
      const int row = b * 32 + (mi << 4) + (fq << 2) + rr;
      const int col = h * 64 + (wave << 4) + fr;
      dst[(size_t)row * 1024 + col] = acc[mi][rr];
    }
}

// ---------------------------------------------------------------------------
// out_gemm: out = tmp2 @ Wo, M=256 N=1024 K=1024, K-split x4 -> O4 fp32.
// grid (8,2,4). A bf16 natural, B = WoT bf16.
// ---------------------------------------------------------------------------
__global__ __launch_bounds__(256) void out_gemm(
    const ushort* __restrict__ tmp2, const ushort* __restrict__ WoT,
    float* __restrict__ O4) {
  __shared__ alignas(16) ushort sA[128 * 40];
  __shared__ alignas(16) ushort sB[128 * 40];
  const int nt = blockIdx.x, mt = blockIdx.y, ks = blockIdx.z;
  const int m0 = mt << 7, n0 = nt << 7, kb = ks << 8;
  const int t = threadIdx.x;
  const int wave = t >> 6, lane = t & 63;
  const int wm = wave >> 1, wn = wave & 1;
  const int fr = lane & 15, fq = lane >> 4;
  const int r = t >> 1, sg = (t & 1) << 4;

  f32x4 acc[4][4];
#pragma unroll
  for (int a = 0; a < 4; ++a)
#pragma unroll
    for (int c = 0; c < 4; ++c) acc[a][c] = (f32x4){0.f, 0.f, 0.f, 0.f};

  for (int it = 0; it < 8; ++it) {
    const int k0 = kb + (it << 5);
    {
      const uint4* s4 = (const uint4*)(tmp2 + (size_t)(m0 + r) * 1024 + k0 + sg);
      *(uint4*)&sA[r * 40 + sg]     = s4[0];
      *(uint4*)&sA[r * 40 + sg + 8] = s4[1];
    }
    {
      const uint4* s4 = (const uint4*)(WoT + (size_t)(n0 + r) * 1024 + k0 + sg);
      *(uint4*)&sB[r * 40 + sg]     = s4[0];
      *(uint4*)&sB[r * 40 + sg + 8] = s4[1];
    }
    __syncthreads();
    bf16x8 aF[4], bF[4];
#pragma unroll
    for (int u = 0; u < 4; ++u) {
      aF[u] = *(const bf16x8*)&sA[((wm << 6) + (u << 4) + fr) * 40 + (fq << 3)];
      bF[u] = *(const bf16x8*)&sB[((wn << 6) + (u << 4) + fr) * 40 + (fq << 3)];
    }
#pragma unroll
    for (int mi = 0; mi < 4; ++mi)
#pragma unroll
      for (int ni = 0; ni < 4; ++ni)
        acc[mi][ni] = __builtin_amdgcn_mfma_f32_16x16x32_bf16(
            aF[mi], bF[ni], acc[mi][ni], 0, 0, 0);
    __syncthreads();
  }
  float* dst = O4 + (size_t)ks * 262144;
#pragma unroll
  for (int mi = 0; mi < 4; ++mi)
#pragma unroll
    for (int ni = 0; ni < 4; ++ni)
#pragma unroll
      for (int rr = 0; rr < 4; ++rr) {
        const int row = m0 + (wm << 6) + (mi << 4) + (fq << 2) + rr;
        const int col = n0 + (wn << 6) + (ni << 4) + fr;
        dst[(size_t)row * 1024 + col] = acc[mi][ni][rr];
      }
}

// ---------------------------------------------------------------------------
__global__ __launch_bounds__(256) void sum_out4(
    const float* __restrict__ O4, float* __restrict__ out) {
  const size_t i4 = ((size_t)blockIdx.x * 256 + threadIdx.x) * 4;
  float4 acc = *(const float4*)(O4 + i4);
#pragma unroll
  for (int p = 1; p < 4; ++p) {
    const float4 v = *(const float4*)(O4 + (size_t)p * 262144 + i4);
    acc.x += v.x; acc.y += v.y; acc.z += v.z; acc.w += v.w;
  }
  *(float4*)(out + i4) = acc;
}

// ---------------------------------------------------------------------------
extern "C" void kernel_launch(void* const* d_in, const int* in_sizes, int n_in,
                              void* d_out, int out_size, void* d_ws, size_t ws_size,
                              hipStream_t stream) {
  const float* hs  = (const float*)d_in[0];
  const float* enc = (const float*)d_in[1];
  const int*   pos = (const int*)d_in[2];
  const float* Wq  = (const float*)d_in[3];
  const float* Wk  = (const float*)d_in[4];
  const float* Wv  = (const float*)d_in[5];
  const float* Wo  = (const float*)d_in[6];
  float* out = (float*)d_out;

  char* w = (char*)d_ws;
  ushort* Xp1  = (ushort*)w;               // gemm1 B
  float*  P    = (float*)w;                // ALIAS: gemm2 partials (Xp1 dead)
  w += (size_t)67108864;
  ushort* Xp2  = (ushort*)w; w += (size_t)67108864;   // gemm2 B
  ushort* qk   = (ushort*)w;               // [8][512][1024] bf16
  ushort* ctx  = (ushort*)w;               // ALIAS: ctx bf16 (qk dead after gemm1)
  w += (size_t)8388608;
  ushort* Sc   = (ushort*)w; w += (size_t)33554432;   // packed scores/attn
  float2* pstat  = (float2*)w; w += (size_t)1048576;
  float2* stats2 = (float2*)w; w += (size_t)32768;
  ushort* qr   = (ushort*)w; w += (size_t)524288;     // [256][1024] bf16
  ushort* tmp2 = (ushort*)w; w += (size_t)524288;     // [256][1024] bf16
  float*  qP   = (float*)w;                // [4][256][1024] fp32
  float*  P2   = (float*)w;                // ALIAS (qP dead after rope_apply)
  float*  O4   = (float*)w;                // ALIAS (P2 dead after reduce_tmp2)
  w += (size_t)4194304;

  // weight packs: WqT/Wkb/WvT/WoT bf16, 2MB each, carved after the 4MB block
  ushort* WqT = (ushort*)w; w += (size_t)2097152;
  ushort* Wkb = (ushort*)w; w += (size_t)2097152;
  ushort* WvT = (ushort*)w; w += (size_t)2097152;
  ushort* WoT = (ushort*)w; w += (size_t)2097152;

  pack_x<<<dim3(16, 32, 8), 256, 0, stream>>>(enc, Xp1, Xp2);
  pack_w<<<dim3(16, 16, 4), 256, 0, stream>>>(Wq, Wk, Wv, Wo, WqT, Wkb, WvT, WoT);
  qrope_gemm<<<dim3(8, 2, 4), 256, 0, stream>>>(hs, WqT, qP);
  rope_apply<<<64, 256, 0, stream>>>(qP, pos, qr);
  qk_gemm<<<dim3(4, 16, 8), 256, 0, stream>>>(qr, Wkb, qk);
  gemm1<<<dim3(8, 32, 4), 256, 0, stream>>>(qk, Xp1, Sc, pstat);
  combine_stats<<<16, 256, 0, stream>>>(pstat, stats2);
  softmax_apply<<<8192, 256, 0, stream>>>(Sc, stats2);
  gemm2<<<dim3(8, 8, 16), 256, 0, stream>>>(Sc, Xp2, P);
  reduce4_bf16<<<2048, 256, 0, stream>>>(P, ctx, 4194304L);     // P -> ctx bf16
  ctxwv_gemm<<<dim3(4, 16, 8), 256, 0, stream>>>(ctx, WvT, P2);
  reduce4_bf16<<<128, 256, 0, stream>>>(P2, tmp2, 262144L);     // P2 -> tmp2 bf16
  out_gemm<<<dim3(8, 2, 4), 256, 0, stream>>>(tmp2, WoT, O4);
  sum_out4<<<256, 256, 0, stream>>>(O4, out);
}

// Round 4
// 442.085 us; speedup vs baseline: 1.2932x; 1.0608x over previous
//
#include <hip/hip_runtime.h>

// ---------------------------------------------------------------------------
// R4: BK=64 K-loops (half the barriers), softmax fused into gemm2 A-staging,
// K-split partial sums folded into consumers' staging. 10 kernels (was 14).
// ---------------------------------------------------------------------------

typedef float  f32x4  __attribute__((ext_vector_type(4)));
typedef __bf16 bf16x8 __attribute__((ext_vector_type(8)));

__device__ __forceinline__ ushort f2b(float x) {
  union { float f; unsigned u; } v; v.f = x;
  unsigned r = (v.u + 0x7fffu + ((v.u >> 16) & 1u)) >> 16;
  return (ushort)r;
}
__device__ __forceinline__ float b2f(ushort h) {
  union { unsigned u; float f; } v; v.u = ((unsigned)h) << 16; return v.f;
}
__device__ __forceinline__ void unpack2(unsigned v, float& lo, float& hi) {
  union { unsigned u; float f; } a, b;
  a.u = v << 16; b.u = v & 0xffff0000u;
  lo = a.f; hi = b.f;
}
__device__ __forceinline__ unsigned packb(float a, float b) {
  return (unsigned)f2b(a) | ((unsigned)f2b(b) << 16);
}
__device__ __forceinline__ int swz(int r) { return (r & 3) ^ ((r >> 2) & 3); }

__device__ __forceinline__ void gload16(const void* g, void* l) {
  __builtin_amdgcn_global_load_lds(
      (const __attribute__((address_space(1))) void*)g,
      (__attribute__((address_space(3))) void*)l, 16, 0, 0);
}

// ---------------------------------------------------------------------------
// K1: pack X (fp32) -> Xp1 (gemm1 B packed) and Xp2 (gemm2 B packed).
// (unchanged from R2/R3)
// ---------------------------------------------------------------------------
__global__ __launch_bounds__(256) void pack_x(
    const float* __restrict__ X, ushort* __restrict__ Xp1, ushort* __restrict__ Xp2) {
  const int z = blockIdx.z, jb = blockIdx.y, cb = blockIdx.x;
  const int t = threadIdx.x;
  __shared__ ushort sT[128 * 72];

#pragma unroll
  for (int rep = 0; rep < 2; ++rep) {
    const int j  = rep * 64 + (t >> 2);
    const int c0 = (t & 3) << 4;
    const float4* src = (const float4*)(X + ((size_t)z * 4096 + jb * 128 + j) * 1024 + cb * 64 + c0);
#pragma unroll
    for (int q = 0; q < 4; ++q) {
      const float4 v = src[q];
      ushort4 w; w.x = f2b(v.x); w.y = f2b(v.y); w.z = f2b(v.z); w.w = f2b(v.w);
      *(ushort4*)&sT[j * 72 + c0 + q * 4] = w;
    }
  }
  __syncthreads();

  ushort* o1 = Xp1 + ((size_t)(z * 32 + jb) * 32 + cb * 2) * 4096;
#pragma unroll
  for (int q = 0; q < 4; ++q) {
    const int kih = q >> 1;
    const int r   = ((q & 1) << 6) + (t >> 2);
    const int p   = t & 3;
    const int lc  = p ^ swz(r);
    const uint4 v = *(const uint4*)&sT[r * 72 + kih * 32 + lc * 8];
    *(uint4*)&o1[(size_t)kih * 4096 + ((size_t)(q & 1) << 11) + (size_t)t * 8] = v;
  }

  ushort* o2 = Xp2 + (((size_t)(z * 8 + (cb >> 1)) * 128 + jb * 4) * 4096) + ((size_t)(cb & 1) << 11);
#pragma unroll
  for (int q = 0; q < 4; ++q) {
    const int cl = t >> 2;
    const int p2 = t & 3;
    const int lj = p2 ^ swz(cl);
    union { ushort u[8]; uint4 v; } pk;
#pragma unroll
    for (int jj = 0; jj < 8; ++jj) pk.u[jj] = sT[(q * 32 + lj * 8 + jj) * 72 + cl];
    *(uint4*)&o2[(size_t)q * 4096 + (size_t)t * 8] = pk.v;
  }
}

// ---------------------------------------------------------------------------
// pack_w: cast weights to bf16. 0:Wq->WqT, 1:Wk->Wkb, 2:Wv->WvT, 3:Wo->WoT.
// ---------------------------------------------------------------------------
__global__ __launch_bounds__(256) void pack_w(
    const float* __restrict__ Wq, const float* __restrict__ Wk,
    const float* __restrict__ Wv, const float* __restrict__ Wo,
    ushort* __restrict__ WqT, ushort* __restrict__ Wkb,
    ushort* __restrict__ WvT, ushort* __restrict__ WoT) {
  const int wsel = blockIdx.z;
  const float* src = (wsel == 0) ? Wq : (wsel == 1) ? Wk : (wsel == 2) ? Wv : Wo;
  const int row0 = blockIdx.y << 6, col0 = blockIdx.x << 6;
  const int t = threadIdx.x;
  __shared__ ushort sT[64 * 72];
  const int r = t >> 2, c0 = (t & 3) << 4;

  union { ushort u[16]; uint4 v[2]; } pk;
  const float4* s4 = (const float4*)(src + (size_t)(row0 + r) * 1024 + col0 + c0);
#pragma unroll
  for (int q = 0; q < 4; ++q) {
    const float4 v = s4[q];
    pk.u[q*4+0] = f2b(v.x); pk.u[q*4+1] = f2b(v.y);
    pk.u[q*4+2] = f2b(v.z); pk.u[q*4+3] = f2b(v.w);
  }
  if (wsel == 1) {
    ushort* dst = Wkb + (size_t)(row0 + r) * 1024 + col0 + c0;
    *(uint4*)dst = pk.v[0];
    *(uint4*)(dst + 8) = pk.v[1];
  } else {
#pragma unroll
    for (int q = 0; q < 16; ++q) sT[r * 72 + c0 + q] = pk.u[q];
    __syncthreads();
    ushort* dst = (wsel == 0) ? WqT : (wsel == 2) ? WvT : WoT;
    union { ushort u[16]; uint4 v[2]; } o;
#pragma unroll
    for (int q = 0; q < 16; ++q) o.u[q] = sT[(c0 + q) * 72 + r];
    ushort* d = dst + (size_t)(col0 + r) * 1024 + row0 + c0;
    *(uint4*)d = o.v[0];
    *(uint4*)(d + 8) = o.v[1];
  }
}

// ---------------------------------------------------------------------------
// qrope_gemm: q = hs @ Wq, K-split x4 -> qP fp32 [4][256][1024]. grid (8,2,4).
// (unchanged from R3)
// ---------------------------------------------------------------------------
__global__ __launch_bounds__(256) void qrope_gemm(
    const float* __restrict__ hs, const ushort* __restrict__ WqT,
    float* __restrict__ qP) {
  __shared__ alignas(16) ushort sA[128 * 40];
  __shared__ alignas(16) ushort sB[128 * 40];
  const int nt = blockIdx.x, mt = blockIdx.y, ks = blockIdx.z;
  const int m0 = mt << 7, n0 = nt << 7, kb = ks << 8;
  const int t = threadIdx.x;
  const int wave = t >> 6, lane = t & 63;
  const int wm = wave >> 1, wn = wave & 1;
  const int fr = lane & 15, fq = lane >> 4;
  const int r = t >> 1, sg = (t & 1) << 4;

  f32x4 acc[4][4];
#pragma unroll
  for (int a = 0; a < 4; ++a)
#pragma unroll
    for (int c = 0; c < 4; ++c) acc[a][c] = (f32x4){0.f, 0.f, 0.f, 0.f};

  for (int it = 0; it < 8; ++it) {
    const int k0 = kb + (it << 5);
    {
      const float4* s4 = (const float4*)(hs + (size_t)(m0 + r) * 1024 + k0 + sg);
      union { ushort u[16]; uint4 v[2]; } pk;
#pragma unroll
      for (int q = 0; q < 4; ++q) {
        const float4 v = s4[q];
        pk.u[q*4+0] = f2b(v.x); pk.u[q*4+1] = f2b(v.y);
        pk.u[q*4+2] = f2b(v.z); pk.u[q*4+3] = f2b(v.w);
      }
      *(uint4*)&sA[r * 40 + sg]     = pk.v[0];
      *(uint4*)&sA[r * 40 + sg + 8] = pk.v[1];
    }
    {
      const uint4* s4 = (const uint4*)(WqT + (size_t)(n0 + r) * 1024 + k0 + sg);
      *(uint4*)&sB[r * 40 + sg]     = s4[0];
      *(uint4*)&sB[r * 40 + sg + 8] = s4[1];
    }
    __syncthreads();
    bf16x8 aF[4], bF[4];
#pragma unroll
    for (int u = 0; u < 4; ++u) {
      aF[u] = *(const bf16x8*)&sA[((wm << 6) + (u << 4) + fr) * 40 + (fq << 3)];
      bF[u] = *(const bf16x8*)&sB[((wn << 6) + (u << 4) + fr) * 40 + (fq << 3)];
    }
#pragma unroll
    for (int mi = 0; mi < 4; ++mi)
#pragma unroll
      for (int ni = 0; ni < 4; ++ni)
        acc[mi][ni] = __builtin_amdgcn_mfma_f32_16x16x32_bf16(
            aF[mi], bF[ni], acc[mi][ni], 0, 0, 0);
    __syncthreads();
  }
  float* dst = qP + (size_t)ks * 262144;
#pragma unroll
  for (int mi = 0; mi < 4; ++mi)
#pragma unroll
    for (int ni = 0; ni < 4; ++ni)
#pragma unroll
      for (int rr = 0; rr < 4; ++rr) {
        const int row = m0 + (wm << 6) + (mi << 4) + (fq << 2) + rr;
        const int col = n0 + (wn << 6) + (ni << 4) + fr;
        dst[(size_t)row * 1024 + col] = acc[mi][ni][rr];
      }
}

// ---------------------------------------------------------------------------
// qk_rope_gemm (merged rope_apply + qk_gemm): per (nc,h,b): sA = bf16(RoPE(
// sum_ks qP slice)*0.125); sB = Wkb head-slice; qk = sA @ sB^T.
// grid (4 nc, 16 h, 8 b) = 512 blocks.
// ---------------------------------------------------------------------------
__global__ __launch_bounds__(256) void qk_rope_gemm(
    const float* __restrict__ qP, const ushort* __restrict__ Wkb,
    const int* __restrict__ pos, ushort* __restrict__ qk) {
  __shared__ float s_qf[32 * 68];
  __shared__ alignas(16) ushort sA[32 * 72];
  __shared__ alignas(16) ushort sB[256 * 72];
  const int nc = blockIdx.x, h = blockIdx.y, b = blockIdx.z;
  const int t = threadIdx.x;
  const int i = t >> 3, d0 = (t & 7) << 3;

  // stage raw q head-slice (sum of 4 K-split partials), fp32
  {
    float s[8];
#pragma unroll
    for (int j = 0; j < 8; ++j) s[j] = 0.f;
#pragma unroll
    for (int p = 0; p < 4; ++p) {
      const float* base = qP + (size_t)p * 262144 + (size_t)(b * 32 + i) * 1024 + h * 64 + d0;
      const float4 a0 = *(const float4*)base;
      const float4 a1 = *(const float4*)(base + 4);
      s[0]+=a0.x; s[1]+=a0.y; s[2]+=a0.z; s[3]+=a0.w;
      s[4]+=a1.x; s[5]+=a1.y; s[6]+=a1.z; s[7]+=a1.w;
    }
#pragma unroll
    for (int j = 0; j < 8; ++j) s_qf[i * 68 + d0 + j] = s[j];
  }
  // stage B: Wkb rows nc*256..+256, head cols
#pragma unroll
  for (int p = 0; p < 8; ++p) {
    const int rr = (t >> 3) + p * 32, seg = (t & 7) << 3;
    *(uint4*)&sB[rr * 72 + seg] =
        *(const uint4*)(Wkb + (size_t)(nc * 256 + rr) * 1024 + h * 64 + seg);
  }
  __syncthreads();

  // RoPE in LDS -> sA bf16 (fold 0.125). int64/int32 pos hedge.
  {
    unsigned oddor = 0;
    for (int j = 1; j < 256; j += 2) oddor |= (unsigned)pos[j];
    const int m = b * 32 + i;
    const int p = (oddor == 0) ? pos[2 * m] : pos[m];
    const float pf = (float)p;
    union { ushort u16[8]; uint4 v; } o;
#pragma unroll
    for (int j = 0; j < 8; ++j) {
      const int d = d0 + j;
      const int f = d & 31;
      const float inv = powf(10000.0f, -(float)f * (1.0f / 32.0f));
      float sn, cs; sincosf(pf * inv, &sn, &cs);
      const float x  = s_qf[i * 68 + d];
      const float xp = s_qf[i * 68 + (d ^ 32)];
      const float v  = (d < 32) ? (x * cs - xp * sn) : (x * cs + xp * sn);
      o.u16[j] = f2b(v * 0.125f);
    }
    *(uint4*)&sA[i * 72 + d0] = o.v;
  }
  __syncthreads();

  const int wave = t >> 6, lane = t & 63;
  const int fr = lane & 15, fq = lane >> 4;
  f32x4 acc[2][4];
#pragma unroll
  for (int a = 0; a < 2; ++a)
#pragma unroll
    for (int c = 0; c < 4; ++c) acc[a][c] = (f32x4){0.f, 0.f, 0.f, 0.f};

#pragma unroll
  for (int ki = 0; ki < 2; ++ki) {
    bf16x8 aF[2], bF[4];
#pragma unroll
    for (int mi = 0; mi < 2; ++mi)
      aF[mi] = *(const bf16x8*)&sA[((mi << 4) + fr) * 72 + (ki << 5) + (fq << 3)];
#pragma unroll
    for (int ni = 0; ni < 4; ++ni)
      bF[ni] = *(const bf16x8*)&sB[((wave << 6) + (ni << 4) + fr) * 72 + (ki << 5) + (fq << 3)];
#pragma unroll
    for (int mi = 0; mi < 2; ++mi)
#pragma unroll
      for (int ni = 0; ni < 4; ++ni)
        acc[mi][ni] = __builtin_amdgcn_mfma_f32_16x16x32_bf16(
            aF[mi], bF[ni], acc[mi][ni], 0, 0, 0);
  }
#pragma unroll
  for (int mi = 0; mi < 2; ++mi)
#pragma unroll
    for (int ni = 0; ni < 4; ++ni)
#pragma unroll
      for (int rr = 0; rr < 4; ++rr) {
        const int row = h * 32 + (mi << 4) + (fq << 2) + rr;
        const int col = nc * 256 + (wave << 6) + (ni << 4) + fr;
        qk[((size_t)b * 512 + row) * 1024 + col] = f2b(acc[mi][ni][rr]);
      }
}

// ---------------------------------------------------------------------------
// G1: scores = qk @ X^T, BK=64 (16 iters, 32 MFMA per barrier-pair).
// Packed-swizzled Sc output + per-row (max,sumexp) partial stats.
// grid (8 z, 32 nty, 4 mt), 256 thr, LDS 32KB.
// ---------------------------------------------------------------------------
__global__ __launch_bounds__(256) void gemm1(
    const ushort* __restrict__ qk, const ushort* __restrict__ Xp1,
    ushort* __restrict__ Sc, float2* __restrict__ pstat) {
  __shared__ alignas(16) ushort sA[8192];
  __shared__ alignas(16) ushort sB[8192];
  __shared__ float sMx[256], sSm[256];
  const int z = blockIdx.x, nty = blockIdx.y, mt = blockIdx.z;
  const int tid = threadIdx.x;
  const int wave = tid >> 6, lane = tid & 63;
  const int wm = wave >> 1, wn = wave & 1;
  const int fr = lane & 15, fq = lane >> 4;
  const int sfr = swz(fr);

  const ushort* Ab = qk + ((size_t)z * 512 + mt * 128) * 1024;
  const ushort* Bb = Xp1 + ((size_t)(z * 32 + nty) * 32) * 4096;

  // A staging (natural qk -> packed LDS): per round j: LDS idx = wave*2048+j*512+lane*8
  // ki = wave>>1, row = (wave&1)*64 + j*16 + lane/4, slot = lane&3
  int arow[4], aoff[4];
#pragma unroll
  for (int j = 0; j < 4; ++j) {
    const int rowA = ((wave & 1) << 6) + (j << 4) + (lane >> 2);
    arow[j] = rowA;
    aoff[j] = ((wave >> 1) << 5) + (((lane & 3) ^ swz(rowA)) << 3);
  }

  f32x4 acc[4][4];
#pragma unroll
  for (int a = 0; a < 4; ++a)
#pragma unroll
    for (int c = 0; c < 4; ++c) acc[a][c] = (f32x4){0.f, 0.f, 0.f, 0.f};

  for (int it = 0; it < 16; ++it) {
    const int k0 = it << 6;
#pragma unroll
    for (int j = 0; j < 4; ++j) {
      gload16(Bb + (size_t)it * 8192 + wave * 2048 + j * 512 + lane * 8,
              &sB[wave * 2048 + j * 512]);
      gload16(Ab + (size_t)arow[j] * 1024 + k0 + aoff[j],
              &sA[wave * 2048 + j * 512]);
    }
    __syncthreads();
#pragma unroll
    for (int kk = 0; kk < 2; ++kk) {
      bf16x8 aF[4], bF[4];
#pragma unroll
      for (int u = 0; u < 4; ++u) {
        aF[u] = *(const bf16x8*)&sA[kk * 4096 + ((wm << 6) + (u << 4) + fr) * 32 + ((fq ^ sfr) << 3)];
        bF[u] = *(const bf16x8*)&sB[kk * 4096 + ((wn << 6) + (u << 4) + fr) * 32 + ((fq ^ sfr) << 3)];
      }
#pragma unroll
      for (int mi = 0; mi < 4; ++mi)
#pragma unroll
        for (int ni = 0; ni < 4; ++ni)
          acc[mi][ni] = __builtin_amdgcn_mfma_f32_16x16x32_bf16(
              aF[mi], bF[ni], acc[mi][ni], 0, 0, 0);
    }
    __syncthreads();
  }

  ushort* ScB = Sc + (size_t)(z * 4 + mt) * 524288;
#pragma unroll
  for (int mi = 0; mi < 4; ++mi)
#pragma unroll
    for (int ni = 0; ni < 4; ++ni)
#pragma unroll
      for (int r = 0; r < 4; ++r) {
        const int row = (wm << 6) + (mi << 4) + (fq << 2) + r;
        const int col = (wn << 6) + (ni << 4) + fr;
        const int ki  = (nty << 2) + (col >> 5);
        const int p   = ((col >> 3) & 3) ^ r ^ fq;
        const ushort hb = f2b(acc[mi][ni][r]);
        ScB[(size_t)ki * 4096 + row * 32 + p * 8 + (fr & 7)] = hb;
        acc[mi][ni][r] = b2f(hb);
      }

#pragma unroll
  for (int mi = 0; mi < 4; ++mi)
#pragma unroll
    for (int r = 0; r < 4; ++r) {
      float m4 = fmaxf(fmaxf(acc[mi][0][r], acc[mi][1][r]),
                       fmaxf(acc[mi][2][r], acc[mi][3][r]));
#pragma unroll
      for (int o = 1; o < 16; o <<= 1) m4 = fmaxf(m4, __shfl_xor(m4, o));
      float s4 = __expf(acc[mi][0][r] - m4) + __expf(acc[mi][1][r] - m4) +
                 __expf(acc[mi][2][r] - m4) + __expf(acc[mi][3][r] - m4);
#pragma unroll
      for (int o = 1; o < 16; o <<= 1) s4 += __shfl_xor(s4, o);
      if (fr == 0) {
        const int row = (wm << 6) + (mi << 4) + (fq << 2) + r;
        sMx[row * 2 + wn] = m4;
        sSm[row * 2 + wn] = s4;
      }
    }
  __syncthreads();
  if (tid < 128) {
    const float m0 = sMx[tid * 2], m1 = sMx[tid * 2 + 1];
    const float M = fmaxf(m0, m1);
    const float S = sSm[tid * 2] * __expf(m0 - M) + sSm[tid * 2 + 1] * __expf(m1 - M);
    pstat[((size_t)(z * 512 + mt * 128 + tid)) * 32 + nty] = make_float2(M, S);
  }
}

// ---------------------------------------------------------------------------
__global__ __launch_bounds__(256) void combine_stats(
    const float2* __restrict__ pstat, float2* __restrict__ stats2) {
  const int g = blockIdx.x * 256 + threadIdx.x;
  const float2* p = pstat + (size_t)g * 32;
  float M = -1e30f;
#pragma unroll
  for (int i = 0; i < 32; ++i) M = fmaxf(M, p[i].x);
  float S = 0.f;
#pragma unroll
  for (int i = 0; i < 32; ++i) S += p[i].y * __expf(p[i].x - M);
  stats2[g] = make_float2(M, 1.0f / S);
}

// ---------------------------------------------------------------------------
// G2 fused: ctx partials = softmax(Sc) @ X. A-staging applies exp((x-M))*invS
// inline (VGPR path, row stats iteration-invariant per lane); B via
// global_load_lds from Xp2. BK=64, K-split x2. grid (8 z, 8 nty, 4mt*2s).
// ---------------------------------------------------------------------------
__global__ __launch_bounds__(256) void gemm2f(
    const ushort* __restrict__ Sc, const ushort* __restrict__ Xp2,
    const float2* __restrict__ stats2, float* __restrict__ P) {
  __shared__ alignas(16) ushort sA[8192];
  __shared__ alignas(16) ushort sB[8192];
  const int z = blockIdx.x, nty = blockIdx.y;
  const int mt = blockIdx.z & 3, s = blockIdx.z >> 2;
  const int tid = threadIdx.x;
  const int wave = tid >> 6, lane = tid & 63;
  const int wm = wave >> 1, wn = wave & 1;
  const int fr = lane & 15, fq = lane >> 4;
  const int sfr = swz(fr);

  const ushort* Ab = Sc + (size_t)(z * 4 + mt) * 524288 + (size_t)s * 262144;
  const ushort* Bb = Xp2 + ((size_t)(z * 8 + nty) * 128 + s * 64) * 4096;

  // lane's two staged rows (iteration-invariant): r0 = t/4, r1 = 64 + t/4
  const float2 st0 = stats2[z * 512 + mt * 128 + (tid >> 2)];
  const float2 st1 = stats2[z * 512 + mt * 128 + 64 + (tid >> 2)];

  f32x4 acc[4][4];
#pragma unroll
  for (int a = 0; a < 4; ++a)
#pragma unroll
    for (int c = 0; c < 4; ++c) acc[a][c] = (f32x4){0.f, 0.f, 0.f, 0.f};

  for (int it = 0; it < 32; ++it) {
    // B: async global->LDS (linear packed)
#pragma unroll
    for (int j = 0; j < 4; ++j)
      gload16(Bb + (size_t)it * 8192 + wave * 2048 + j * 512 + lane * 8,
              &sB[wave * 2048 + j * 512]);
    // A: VGPR staging with fused softmax
#pragma unroll
    for (int j = 0; j < 4; ++j) {
      const uint4 v = *(const uint4*)(Ab + (size_t)it * 8192 + j * 2048 + tid * 8);
      const float M   = (j & 1) ? st1.x : st0.x;
      const float inv = (j & 1) ? st1.y : st0.y;
      float x0,x1,x2,x3,x4,x5,x6,x7;
      unpack2(v.x, x0, x1); unpack2(v.y, x2, x3);
      unpack2(v.z, x4, x5); unpack2(v.w, x6, x7);
      uint4 o;
      o.x = packb(__expf(x0 - M) * inv, __expf(x1 - M) * inv);
      o.y = packb(__expf(x2 - M) * inv, __expf(x3 - M) * inv);
      o.z = packb(__expf(x4 - M) * inv, __expf(x5 - M) * inv);
      o.w = packb(__expf(x6 - M) * inv, __expf(x7 - M) * inv);
      *(uint4*)&sA[j * 2048 + tid * 8] = o;
    }
    __syncthreads();
#pragma unroll
    for (int kk = 0; kk < 2; ++kk) {
      bf16x8 aF[4], bF[4];
#pragma unroll
      for (int u = 0; u < 4; ++u) {
        aF[u] = *(const bf16x8*)&sA[kk * 4096 + ((wm << 6) + (u << 4) + fr) * 32 + ((fq ^ sfr) << 3)];
        bF[u] = *(const bf16x8*)&sB[kk * 4096 + ((wn << 6) + (u << 4) + fr) * 32 + ((fq ^ sfr) << 3)];
      }
#pragma unroll
      for (int mi = 0; mi < 4; ++mi)
#pragma unroll
        for (int ni = 0; ni < 4; ++ni)
          acc[mi][ni] = __builtin_amdgcn_mfma_f32_16x16x32_bf16(
              aF[mi], bF[ni], acc[mi][ni], 0, 0, 0);
    }
    __syncthreads();
  }

  float* Pb = P + (((size_t)(s * 8 + z) * 512) + mt * 128) * 1024 + nty * 128;
#pragma unroll
  for (int mi = 0; mi < 4; ++mi)
#pragma unroll
    for (int ni = 0; ni < 4; ++ni)
#pragma unroll
      for (int r = 0; r < 4; ++r) {
        const int row = (wm << 6) + (mi << 4) + (fq << 2) + r;
        const int col = (wn << 6) + (ni << 4) + fr;
        Pb[(size_t)row * 1024 + col] = acc[mi][ni][r];
      }
}

// ---------------------------------------------------------------------------
// ctxwv_gemm (folds P0+P1 sum into A-staging): per (ks,h,b): partial
// tmp2 = ctx @ Wv_h over K-window ks*256. -> P2 fp32 [4][256][1024].
// ---------------------------------------------------------------------------
__global__ __launch_bounds__(256) void ctxwv_gemm(
    const float* __restrict__ P, const ushort* __restrict__ WvT,
    float* __restrict__ P2) {
  __shared__ alignas(16) ushort sA[32 * 264];
  __shared__ alignas(16) ushort sB[64 * 264];
  const int ks = blockIdx.x, h = blockIdx.y, b = blockIdx.z;
  const int kb = ks << 8;
  const int t = threadIdx.x;
#pragma unroll
  for (int q = 0; q < 4; ++q) {
    const int i = t >> 3, seg = ((t & 7) + q * 8) << 3;
    const float* p0 = P + ((size_t)(0 * 8 + b) * 512 + h * 32 + i) * 1024 + kb + seg;
    const float* p1 = P + ((size_t)(1 * 8 + b) * 512 + h * 32 + i) * 1024 + kb + seg;
    const float4 a0 = *(const float4*)p0,       a1 = *(const float4*)(p0 + 4);
    const float4 b0 = *(const float4*)p1,       b1 = *(const float4*)(p1 + 4);
    uint4 o;
    o.x = packb(a0.x + b0.x, a0.y + b0.y);
    o.y = packb(a0.z + b0.z, a0.w + b0.w);
    o.z = packb(a1.x + b1.x, a1.y + b1.y);
    o.w = packb(a1.z + b1.z, a1.w + b1.w);
    *(uint4*)&sA[i * 264 + seg] = o;
  }
#pragma unroll
  for (int p = 0; p < 8; ++p) {
    const int rr = (t >> 3) + (p & 1) * 32;
    const int seg = ((t & 7) + (p >> 1) * 8) << 3;
    *(uint4*)&sB[rr * 264 + seg] =
        *(const uint4*)(WvT + (size_t)(h * 64 + rr) * 1024 + kb + seg);
  }
  __syncthreads();

  const int wave = t >> 6, lane = t & 63;
  const int fr = lane & 15, fq = lane >> 4;
  f32x4 acc[2];
  acc[0] = (f32x4){0.f, 0.f, 0.f, 0.f};
  acc[1] = (f32x4){0.f, 0.f, 0.f, 0.f};

#pragma unroll
  for (int ki = 0; ki < 8; ++ki) {
    bf16x8 bFr = *(const bf16x8*)&sB[((wave << 4) + fr) * 264 + (ki << 5) + (fq << 3)];
#pragma unroll
    for (int mi = 0; mi < 2; ++mi) {
      bf16x8 aF = *(const bf16x8*)&sA[((mi << 4) + fr) * 264 + (ki << 5) + (fq << 3)];
      acc[mi] = __builtin_amdgcn_mfma_f32_16x16x32_bf16(aF, bFr, acc[mi], 0, 0, 0);
    }
  }
  float* dst = P2 + (size_t)ks * 262144;
#pragma unroll
  for (int mi = 0; mi < 2; ++mi)
#pragma unroll
    for (int rr = 0; rr < 4; ++rr) {
      const int row = b * 32 + (mi << 4) + (fq << 2) + rr;
      const int col = h * 64 + (wave << 4) + fr;
      dst[(size_t)row * 1024 + col] = acc[mi][rr];
    }
}

// ---------------------------------------------------------------------------
// out_gemm (folds P2 4-way sum into A-staging): out partials = tmp2 @ Wo,
// K-split x4 -> O4 fp32. grid (8,2,4).
// ---------------------------------------------------------------------------
__global__ __launch_bounds__(256) void out_gemm(
    const float* __restrict__ P2, const ushort* __restrict__ WoT,
    float* __restrict__ O4) {
  __shared__ alignas(16) ushort sA[128 * 40];
  __shared__ alignas(16) ushort sB[128 * 40];
  const int nt = blockIdx.x, mt = blockIdx.y, ks = blockIdx.z;
  const int m0 = mt << 7, n0 = nt << 7, kb = ks << 8;
  const int t = threadIdx.x;
  const int wave = t >> 6, lane = t & 63;
  const int wm = wave >> 1, wn = wave & 1;
  const int fr = lane & 15, fq = lane >> 4;
  const int r = t >> 1, sg = (t & 1) << 4;

  f32x4 acc[4][4];
#pragma unroll
  for (int a = 0; a < 4; ++a)
#pragma unroll
    for (int c = 0; c < 4; ++c) acc[a][c] = (f32x4){0.f, 0.f, 0.f, 0.f};

  for (int it = 0; it < 8; ++it) {
    const int k0 = kb + (it << 5);
    {
      float s[16];
#pragma unroll
      for (int j = 0; j < 16; ++j) s[j] = 0.f;
#pragma unroll
      for (int p = 0; p < 4; ++p) {
        const float* base = P2 + (size_t)p * 262144 + (size_t)(m0 + r) * 1024 + k0 + sg;
#pragma unroll
        for (int q = 0; q < 4; ++q) {
          const float4 v = *(const float4*)(base + q * 4);
          s[q*4+0] += v.x; s[q*4+1] += v.y; s[q*4+2] += v.z; s[q*4+3] += v.w;
        }
      }
      uint4 o0, o1;
      o0.x = packb(s[0], s[1]);   o0.y = packb(s[2], s[3]);
      o0.z = packb(s[4], s[5]);   o0.w = packb(s[6], s[7]);
      o1.x = packb(s[8], s[9]);   o1.y = packb(s[10], s[11]);
      o1.z = packb(s[12], s[13]); o1.w = packb(s[14], s[15]);
      *(uint4*)&sA[r * 40 + sg]     = o0;
      *(uint4*)&sA[r * 40 + sg + 8] = o1;
    }
    {
      const uint4* s4 = (const uint4*)(WoT + (size_t)(n0 + r) * 1024 + k0 + sg);
      *(uint4*)&sB[r * 40 + sg]     = s4[0];
      *(uint4*)&sB[r * 40 + sg + 8] = s4[1];
    }
    __syncthreads();
    bf16x8 aF[4], bF[4];
#pragma unroll
    for (int u = 0; u < 4; ++u) {
      aF[u] = *(const bf16x8*)&sA[((wm << 6) + (u << 4) + fr) * 40 + (fq << 3)];
      bF[u] = *(const bf16x8*)&sB[((wn << 6) + (u << 4) + fr) * 40 + (fq << 3)];
    }
#pragma unroll
    for (int mi = 0; mi < 4; ++mi)
#pragma unroll
      for (int ni = 0; ni < 4; ++ni)
        acc[mi][ni] = __builtin_amdgcn_mfma_f32_16x16x32_bf16(
            aF[mi], bF[ni], acc[mi][ni], 0, 0, 0);
    __syncthreads();
  }
  float* dst = O4 + (size_t)ks * 262144;
#pragma unroll
  for (int mi = 0; mi < 4; ++mi)
#pragma unroll
    for (int ni = 0; ni < 4; ++ni)
#pragma unroll
      for (int rr = 0; rr < 4; ++rr) {
        const int row = m0 + (wm << 6) + (mi << 4) + (fq << 2) + rr;
        const int col = n0 + (wn << 6) + (ni << 4) + fr;
        dst[(size_t)row * 1024 + col] = acc[mi][ni][rr];
      }
}

// ---------------------------------------------------------------------------
__global__ __launch_bounds__(256) void sum_out4(
    const float* __restrict__ O4, float* __restrict__ out) {
  const size_t i4 = ((size_t)blockIdx.x * 256 + threadIdx.x) * 4;
  float4 acc = *(const float4*)(O4 + i4);
#pragma unroll
  for (int p = 1; p < 4; ++p) {
    const float4 v = *(const float4*)(O4 + (size_t)p * 262144 + i4);
    acc.x += v.x; acc.y += v.y; acc.z += v.z; acc.w += v.w;
  }
  *(float4*)(out + i4) = acc;
}

// ---------------------------------------------------------------------------
extern "C" void kernel_launch(void* const* d_in, const int* in_sizes, int n_in,
                              void* d_out, int out_size, void* d_ws, size_t ws_size,
                              hipStream_t stream) {
  const float* hs  = (const float*)d_in[0];
  const float* enc = (const float*)d_in[1];
  const int*   pos = (const int*)d_in[2];
  const float* Wq  = (const float*)d_in[3];
  const float* Wk  = (const float*)d_in[4];
  const float* Wv  = (const float*)d_in[5];
  const float* Wo  = (const float*)d_in[6];
  float* out = (float*)d_out;

  char* w = (char*)d_ws;
  ushort* Xp1  = (ushort*)w;               // gemm1 B (67 MB)
  float*  P    = (float*)w;                // ALIAS: gemm2f partials 33.5MB (Xp1 dead)
  w += (size_t)67108864;
  ushort* Xp2  = (ushort*)w;               // gemm2f B (67 MB)
  float*  P2   = (float*)w;                // ALIAS: ctxwv partials 4MB (Xp2 dead)
  w += (size_t)67108864;
  ushort* qk   = (ushort*)w; w += (size_t)8388608;    // [8][512][1024] bf16
  ushort* Sc   = (ushort*)w; w += (size_t)33554432;   // packed raw scores
  float2* pstat  = (float2*)w; w += (size_t)1048576;
  float2* stats2 = (float2*)w; w += (size_t)32768;
  float*  qP   = (float*)w;                // [4][256][1024] fp32
  float*  O4   = (float*)w;                // ALIAS (qP dead after qk_rope_gemm)
  w += (size_t)4194304;
  ushort* WqT = (ushort*)w; w += (size_t)2097152;
  ushort* Wkb = (ushort*)w; w += (size_t)2097152;
  ushort* WvT = (ushort*)w; w += (size_t)2097152;
  ushort* WoT = (ushort*)w; w += (size_t)2097152;

  pack_x<<<dim3(16, 32, 8), 256, 0, stream>>>(enc, Xp1, Xp2);
  pack_w<<<dim3(16, 16, 4), 256, 0, stream>>>(Wq, Wk, Wv, Wo, WqT, Wkb, WvT, WoT);
  qrope_gemm<<<dim3(8, 2, 4), 256, 0, stream>>>(hs, WqT, qP);
  qk_rope_gemm<<<dim3(4, 16, 8), 256, 0, stream>>>(qP, Wkb, pos, qk);
  gemm1<<<dim3(8, 32, 4), 256, 0, stream>>>(qk, Xp1, Sc, pstat);
  combine_stats<<<16, 256, 0, stream>>>(pstat, stats2);
  gemm2f<<<dim3(8, 8, 8), 256, 0, stream>>>(Sc, Xp2, stats2, P);
  ctxwv_gemm<<<dim3(4, 16, 8), 256, 0, stream>>>(P, WvT, P2);
  out_gemm<<<dim3(8, 2, 4), 256, 0, stream>>>(P2, WoT, O4);
  sum_out4<<<256, 256, 0, stream>>>(O4, out);
}

// Round 5
// 423.496 us; speedup vs baseline: 1.3500x; 1.0439x over previous
//
#include <hip/hip_runtime.h>

// ---------------------------------------------------------------------------
// R5: un-fuse softmax from gemm2 (8x redundant exp made staging VALU-bound:
// VALUBusy 49%). Dedicated apply pass (exp once) + pure gload16 gemm2.
// combine_stats folded into apply; pack_w folded into pack_x. 9 kernels.
// ---------------------------------------------------------------------------

typedef float  f32x4  __attribute__((ext_vector_type(4)));
typedef __bf16 bf16x8 __attribute__((ext_vector_type(8)));

__device__ __forceinline__ ushort f2b(float x) {
  union { float f; unsigned u; } v; v.f = x;
  unsigned r = (v.u + 0x7fffu + ((v.u >> 16) & 1u)) >> 16;
  return (ushort)r;
}
__device__ __forceinline__ float b2f(ushort h) {
  union { unsigned u; float f; } v; v.u = ((unsigned)h) << 16; return v.f;
}
__device__ __forceinline__ void unpack2(unsigned v, float& lo, float& hi) {
  union { unsigned u; float f; } a, b;
  a.u = v << 16; b.u = v & 0xffff0000u;
  lo = a.f; hi = b.f;
}
__device__ __forceinline__ unsigned packb(float a, float b) {
  return (unsigned)f2b(a) | ((unsigned)f2b(b) << 16);
}
__device__ __forceinline__ int swz(int r) { return (r & 3) ^ ((r >> 2) & 3); }

__device__ __forceinline__ void gload16(const void* g, void* l) {
  __builtin_amdgcn_global_load_lds(
      (const __attribute__((address_space(1))) void*)g,
      (__attribute__((address_space(3))) void*)l, 16, 0, 0);
}

// ---------------------------------------------------------------------------
// pack_all: z<8 -> pack X tile into Xp1/Xp2 (unchanged logic); z in {8,9} ->
// pack one 64x64 weight tile (wsel = (z-8)*2 + (y>>4)).
// grid (16, 32, 10), 256 thr.
// ---------------------------------------------------------------------------
__global__ __launch_bounds__(256) void pack_all(
    const float* __restrict__ X, ushort* __restrict__ Xp1, ushort* __restrict__ Xp2,
    const float* __restrict__ Wq, const float* __restrict__ Wk,
    const float* __restrict__ Wv, const float* __restrict__ Wo,
    ushort* __restrict__ WqT, ushort* __restrict__ Wkb,
    ushort* __restrict__ WvT, ushort* __restrict__ WoT) {
  const int t = threadIdx.x;
  if (blockIdx.z < 8) {
    const int z = blockIdx.z, jb = blockIdx.y, cb = blockIdx.x;
    __shared__ ushort sT[128 * 72];
#pragma unroll
    for (int rep = 0; rep < 2; ++rep) {
      const int j  = rep * 64 + (t >> 2);
      const int c0 = (t & 3) << 4;
      const float4* src = (const float4*)(X + ((size_t)z * 4096 + jb * 128 + j) * 1024 + cb * 64 + c0);
#pragma unroll
      for (int q = 0; q < 4; ++q) {
        const float4 v = src[q];
        ushort4 w; w.x = f2b(v.x); w.y = f2b(v.y); w.z = f2b(v.z); w.w = f2b(v.w);
        *(ushort4*)&sT[j * 72 + c0 + q * 4] = w;
      }
    }
    __syncthreads();

    ushort* o1 = Xp1 + ((size_t)(z * 32 + jb) * 32 + cb * 2) * 4096;
#pragma unroll
    for (int q = 0; q < 4; ++q) {
      const int kih = q >> 1;
      const int r   = ((q & 1) << 6) + (t >> 2);
      const int p   = t & 3;
      const int lc  = p ^ swz(r);
      const uint4 v = *(const uint4*)&sT[r * 72 + kih * 32 + lc * 8];
      *(uint4*)&o1[(size_t)kih * 4096 + ((size_t)(q & 1) << 11) + (size_t)t * 8] = v;
    }

    ushort* o2 = Xp2 + (((size_t)(z * 8 + (cb >> 1)) * 128 + jb * 4) * 4096) + ((size_t)(cb & 1) << 11);
#pragma unroll
    for (int q = 0; q < 4; ++q) {
      const int cl = t >> 2;
      const int p2 = t & 3;
      const int lj = p2 ^ swz(cl);
      union { ushort u[8]; uint4 v; } pk;
#pragma unroll
      for (int jj = 0; jj < 8; ++jj) pk.u[jj] = sT[(q * 32 + lj * 8 + jj) * 72 + cl];
      *(uint4*)&o2[(size_t)q * 4096 + (size_t)t * 8] = pk.v;
    }
  } else {
    const int wsel = (blockIdx.z - 8) * 2 + (blockIdx.y >> 4);
    const float* src = (wsel == 0) ? Wq : (wsel == 1) ? Wk : (wsel == 2) ? Wv : Wo;
    const int row0 = (blockIdx.y & 15) << 6, col0 = blockIdx.x << 6;
    __shared__ ushort sW[64 * 72];
    const int r = t >> 2, c0 = (t & 3) << 4;

    union { ushort u[16]; uint4 v[2]; } pk;
    const float4* s4 = (const float4*)(src + (size_t)(row0 + r) * 1024 + col0 + c0);
#pragma unroll
    for (int q = 0; q < 4; ++q) {
      const float4 v = s4[q];
      pk.u[q*4+0] = f2b(v.x); pk.u[q*4+1] = f2b(v.y);
      pk.u[q*4+2] = f2b(v.z); pk.u[q*4+3] = f2b(v.w);
    }
    if (wsel == 1) {
      ushort* dst = Wkb + (size_t)(row0 + r) * 1024 + col0 + c0;
      *(uint4*)dst = pk.v[0];
      *(uint4*)(dst + 8) = pk.v[1];
    } else {
#pragma unroll
      for (int q = 0; q < 16; ++q) sW[r * 72 + c0 + q] = pk.u[q];
      __syncthreads();
      ushort* dst = (wsel == 0) ? WqT : (wsel == 2) ? WvT : WoT;
      union { ushort u[16]; uint4 v[2]; } o;
#pragma unroll
      for (int q = 0; q < 16; ++q) o.u[q] = sW[(c0 + q) * 72 + r];
      ushort* d = dst + (size_t)(col0 + r) * 1024 + row0 + c0;
      *(uint4*)d = o.v[0];
      *(uint4*)(d + 8) = o.v[1];
    }
  }
}

// ---------------------------------------------------------------------------
// qrope_gemm: q = hs @ Wq, K-split x4 -> qP fp32 [4][256][1024]. grid (8,2,4).
// ---------------------------------------------------------------------------
__global__ __launch_bounds__(256) void qrope_gemm(
    const float* __restrict__ hs, const ushort* __restrict__ WqT,
    float* __restrict__ qP) {
  __shared__ alignas(16) ushort sA[128 * 40];
  __shared__ alignas(16) ushort sB[128 * 40];
  const int nt = blockIdx.x, mt = blockIdx.y, ks = blockIdx.z;
  const int m0 = mt << 7, n0 = nt << 7, kb = ks << 8;
  const int t = threadIdx.x;
  const int wave = t >> 6, lane = t & 63;
  const int wm = wave >> 1, wn = wave & 1;
  const int fr = lane & 15, fq = lane >> 4;
  const int r = t >> 1, sg = (t & 1) << 4;

  f32x4 acc[4][4];
#pragma unroll
  for (int a = 0; a < 4; ++a)
#pragma unroll
    for (int c = 0; c < 4; ++c) acc[a][c] = (f32x4){0.f, 0.f, 0.f, 0.f};

  for (int it = 0; it < 8; ++it) {
    const int k0 = kb + (it << 5);
    {
      const float4* s4 = (const float4*)(hs + (size_t)(m0 + r) * 1024 + k0 + sg);
      union { ushort u[16]; uint4 v[2]; } pk;
#pragma unroll
      for (int q = 0; q < 4; ++q) {
        const float4 v = s4[q];
        pk.u[q*4+0] = f2b(v.x); pk.u[q*4+1] = f2b(v.y);
        pk.u[q*4+2] = f2b(v.z); pk.u[q*4+3] = f2b(v.w);
      }
      *(uint4*)&sA[r * 40 + sg]     = pk.v[0];
      *(uint4*)&sA[r * 40 + sg + 8] = pk.v[1];
    }
    {
      const uint4* s4 = (const uint4*)(WqT + (size_t)(n0 + r) * 1024 + k0 + sg);
      *(uint4*)&sB[r * 40 + sg]     = s4[0];
      *(uint4*)&sB[r * 40 + sg + 8] = s4[1];
    }
    __syncthreads();
    bf16x8 aF[4], bF[4];
#pragma unroll
    for (int u = 0; u < 4; ++u) {
      aF[u] = *(const bf16x8*)&sA[((wm << 6) + (u << 4) + fr) * 40 + (fq << 3)];
      bF[u] = *(const bf16x8*)&sB[((wn << 6) + (u << 4) + fr) * 40 + (fq << 3)];
    }
#pragma unroll
    for (int mi = 0; mi < 4; ++mi)
#pragma unroll
      for (int ni = 0; ni < 4; ++ni)
        acc[mi][ni] = __builtin_amdgcn_mfma_f32_16x16x32_bf16(
            aF[mi], bF[ni], acc[mi][ni], 0, 0, 0);
    __syncthreads();
  }
  float* dst = qP + (size_t)ks * 262144;
#pragma unroll
  for (int mi = 0; mi < 4; ++mi)
#pragma unroll
    for (int ni = 0; ni < 4; ++ni)
#pragma unroll
      for (int rr = 0; rr < 4; ++rr) {
        const int row = m0 + (wm << 6) + (mi << 4) + (fq << 2) + rr;
        const int col = n0 + (wn << 6) + (ni << 4) + fr;
        dst[(size_t)row * 1024 + col] = acc[mi][ni][rr];
      }
}

// ---------------------------------------------------------------------------
// qk_rope_gemm: sA = bf16(RoPE(sum_ks qP)*0.125); qk = sA @ Wkb_head^T.
// grid (4 nc, 16 h, 8 b).
// ---------------------------------------------------------------------------
__global__ __launch_bounds__(256) void qk_rope_gemm(
    const float* __restrict__ qP, const ushort* __restrict__ Wkb,
    const int* __restrict__ pos, ushort* __restrict__ qk) {
  __shared__ float s_qf[32 * 68];
  __shared__ alignas(16) ushort sA[32 * 72];
  __shared__ alignas(16) ushort sB[256 * 72];
  const int nc = blockIdx.x, h = blockIdx.y, b = blockIdx.z;
  const int t = threadIdx.x;
  const int i = t >> 3, d0 = (t & 7) << 3;

  {
    float s[8];
#pragma unroll
    for (int j = 0; j < 8; ++j) s[j] = 0.f;
#pragma unroll
    for (int p = 0; p < 4; ++p) {
      const float* base = qP + (size_t)p * 262144 + (size_t)(b * 32 + i) * 1024 + h * 64 + d0;
      const float4 a0 = *(const float4*)base;
      const float4 a1 = *(const float4*)(base + 4);
      s[0]+=a0.x; s[1]+=a0.y; s[2]+=a0.z; s[3]+=a0.w;
      s[4]+=a1.x; s[5]+=a1.y; s[6]+=a1.z; s[7]+=a1.w;
    }
#pragma unroll
    for (int j = 0; j < 8; ++j) s_qf[i * 68 + d0 + j] = s[j];
  }
#pragma unroll
  for (int p = 0; p < 8; ++p) {
    const int rr = (t >> 3) + p * 32, seg = (t & 7) << 3;
    *(uint4*)&sB[rr * 72 + seg] =
        *(const uint4*)(Wkb + (size_t)(nc * 256 + rr) * 1024 + h * 64 + seg);
  }
  __syncthreads();

  {
    // int64 vs int32 layout probe: 16 odd slots suffice (P(all-zero|int32)~0)
    unsigned oddor = 0;
#pragma unroll
    for (int j = 1; j < 32; j += 2) oddor |= (unsigned)pos[j];
    const int m = b * 32 + i;
    const int p = (oddor == 0) ? pos[2 * m] : pos[m];
    const float pf = (float)p;
    union { ushort u16[8]; uint4 v; } o;
#pragma unroll
    for (int j = 0; j < 8; ++j) {
      const int d = d0 + j;
      const int f = d & 31;
      const float inv = powf(10000.0f, -(float)f * (1.0f / 32.0f));
      float sn, cs; sincosf(pf * inv, &sn, &cs);
      const float x  = s_qf[i * 68 + d];
      const float xp = s_qf[i * 68 + (d ^ 32)];
      const float v  = (d < 32) ? (x * cs - xp * sn) : (x * cs + xp * sn);
      o.u16[j] = f2b(v * 0.125f);
    }
    *(uint4*)&sA[i * 72 + d0] = o.v;
  }
  __syncthreads();

  const int wave = t >> 6, lane = t & 63;
  const int fr = lane & 15, fq = lane >> 4;
  f32x4 acc[2][4];
#pragma unroll
  for (int a = 0; a < 2; ++a)
#pragma unroll
    for (int c = 0; c < 4; ++c) acc[a][c] = (f32x4){0.f, 0.f, 0.f, 0.f};

#pragma unroll
  for (int ki = 0; ki < 2; ++ki) {
    bf16x8 aF[2], bF[4];
#pragma unroll
    for (int mi = 0; mi < 2; ++mi)
      aF[mi] = *(const bf16x8*)&sA[((mi << 4) + fr) * 72 + (ki << 5) + (fq << 3)];
#pragma unroll
    for (int ni = 0; ni < 4; ++ni)
      bF[ni] = *(const bf16x8*)&sB[((wave << 6) + (ni << 4) + fr) * 72 + (ki << 5) + (fq << 3)];
#pragma unroll
    for (int mi = 0; mi < 2; ++mi)
#pragma unroll
      for (int ni = 0; ni < 4; ++ni)
        acc[mi][ni] = __builtin_amdgcn_mfma_f32_16x16x32_bf16(
            aF[mi], bF[ni], acc[mi][ni], 0, 0, 0);
  }
#pragma unroll
  for (int mi = 0; mi < 2; ++mi)
#pragma unroll
    for (int ni = 0; ni < 4; ++ni)
#pragma unroll
      for (int rr = 0; rr < 4; ++rr) {
        const int row = h * 32 + (mi << 4) + (fq << 2) + rr;
        const int col = nc * 256 + (wave << 6) + (ni << 4) + fr;
        qk[((size_t)b * 512 + row) * 1024 + col] = f2b(acc[mi][ni][rr]);
      }
}

// ---------------------------------------------------------------------------
// G1: scores = qk @ X^T, BK=64. Packed Sc + per-row (max,sumexp) partials.
// grid (8 z, 32 nty, 4 mt).
// ---------------------------------------------------------------------------
__global__ __launch_bounds__(256) void gemm1(
    const ushort* __restrict__ qk, const ushort* __restrict__ Xp1,
    ushort* __restrict__ Sc, float2* __restrict__ pstat) {
  __shared__ alignas(16) ushort sA[8192];
  __shared__ alignas(16) ushort sB[8192];
  __shared__ float sMx[256], sSm[256];
  const int z = blockIdx.x, nty = blockIdx.y, mt = blockIdx.z;
  const int tid = threadIdx.x;
  const int wave = tid >> 6, lane = tid & 63;
  const int wm = wave >> 1, wn = wave & 1;
  const int fr = lane & 15, fq = lane >> 4;
  const int sfr = swz(fr);

  const ushort* Ab = qk + ((size_t)z * 512 + mt * 128) * 1024;
  const ushort* Bb = Xp1 + ((size_t)(z * 32 + nty) * 32) * 4096;

  int arow[4], aoff[4];
#pragma unroll
  for (int j = 0; j < 4; ++j) {
    const int rowA = ((wave & 1) << 6) + (j << 4) + (lane >> 2);
    arow[j] = rowA;
    aoff[j] = ((wave >> 1) << 5) + (((lane & 3) ^ swz(rowA)) << 3);
  }

  f32x4 acc[4][4];
#pragma unroll
  for (int a = 0; a < 4; ++a)
#pragma unroll
    for (int c = 0; c < 4; ++c) acc[a][c] = (f32x4){0.f, 0.f, 0.f, 0.f};

  for (int it = 0; it < 16; ++it) {
    const int k0 = it << 6;
#pragma unroll
    for (int j = 0; j < 4; ++j) {
      gload16(Bb + (size_t)it * 8192 + wave * 2048 + j * 512 + lane * 8,
              &sB[wave * 2048 + j * 512]);
      gload16(Ab + (size_t)arow[j] * 1024 + k0 + aoff[j],
              &sA[wave * 2048 + j * 512]);
    }
    __syncthreads();
#pragma unroll
    for (int kk = 0; kk < 2; ++kk) {
      bf16x8 aF[4], bF[4];
#pragma unroll
      for (int u = 0; u < 4; ++u) {
        aF[u] = *(const bf16x8*)&sA[kk * 4096 + ((wm << 6) + (u << 4) + fr) * 32 + ((fq ^ sfr) << 3)];
        bF[u] = *(const bf16x8*)&sB[kk * 4096 + ((wn << 6) + (u << 4) + fr) * 32 + ((fq ^ sfr) << 3)];
      }
#pragma unroll
      for (int mi = 0; mi < 4; ++mi)
#pragma unroll
        for (int ni = 0; ni < 4; ++ni)
          acc[mi][ni] = __builtin_amdgcn_mfma_f32_16x16x32_bf16(
              aF[mi], bF[ni], acc[mi][ni], 0, 0, 0);
    }
    __syncthreads();
  }

  ushort* ScB = Sc + (size_t)(z * 4 + mt) * 524288;
#pragma unroll
  for (int mi = 0; mi < 4; ++mi)
#pragma unroll
    for (int ni = 0; ni < 4; ++ni)
#pragma unroll
      for (int r = 0; r < 4; ++r) {
        const int row = (wm << 6) + (mi << 4) + (fq << 2) + r;
        const int col = (wn << 6) + (ni << 4) + fr;
        const int ki  = (nty << 2) + (col >> 5);
        const int p   = ((col >> 3) & 3) ^ r ^ fq;
        const ushort hb = f2b(acc[mi][ni][r]);
        ScB[(size_t)ki * 4096 + row * 32 + p * 8 + (fr & 7)] = hb;
        acc[mi][ni][r] = b2f(hb);
      }

#pragma unroll
  for (int mi = 0; mi < 4; ++mi)
#pragma unroll
    for (int r = 0; r < 4; ++r) {
      float m4 = fmaxf(fmaxf(acc[mi][0][r], acc[mi][1][r]),
                       fmaxf(acc[mi][2][r], acc[mi][3][r]));
#pragma unroll
      for (int o = 1; o < 16; o <<= 1) m4 = fmaxf(m4, __shfl_xor(m4, o));
      float s4 = __expf(acc[mi][0][r] - m4) + __expf(acc[mi][1][r] - m4) +
                 __expf(acc[mi][2][r] - m4) + __expf(acc[mi][3][r] - m4);
#pragma unroll
      for (int o = 1; o < 16; o <<= 1) s4 += __shfl_xor(s4, o);
      if (fr == 0) {
        const int row = (wm << 6) + (mi << 4) + (fq << 2) + r;
        sMx[row * 2 + wn] = m4;
        sSm[row * 2 + wn] = s4;
      }
    }
  __syncthreads();
  if (tid < 128) {
    const float m0 = sMx[tid * 2], m1 = sMx[tid * 2 + 1];
    const float M = fmaxf(m0, m1);
    const float S = sSm[tid * 2] * __expf(m0 - M) + sSm[tid * 2 + 1] * __expf(m1 - M);
    pstat[((size_t)(z * 512 + mt * 128 + tid)) * 32 + nty] = make_float2(M, S);
  }
}

// ---------------------------------------------------------------------------
// softmax_apply2: combine stats (prologue) + apply exp in place on packed Sc.
// grid (32 zmt, 16 kg), 256 thr; each block: 8 ki-slabs of 8KB.
// ---------------------------------------------------------------------------
__global__ __launch_bounds__(256) void softmax_apply2(
    ushort* __restrict__ Sc, const float2* __restrict__ pstat) {
  __shared__ float sM[128], sI[128];
  const int zmt = blockIdx.x, kg = blockIdx.y;
  const int t = threadIdx.x;
  if (t < 128) {
    const float2* p = pstat + ((size_t)zmt * 128 + t) * 32;
    float M = -1e30f;
#pragma unroll
    for (int i = 0; i < 32; ++i) M = fmaxf(M, p[i].x);
    float S = 0.f;
#pragma unroll
    for (int i = 0; i < 32; ++i) S += p[i].y * __expf(p[i].x - M);
    sM[t] = M; sI[t] = 1.0f / S;
  }
  __syncthreads();
  const int r = t >> 1;
  const float M = sM[r], inv = sI[r];
  ushort* base = Sc + ((size_t)zmt * 128 + kg * 8) * 4096 + t * 16;
#pragma unroll
  for (int kt = 0; kt < 8; ++kt) {
    uint4 v0 = *(uint4*)base;
    uint4 v1 = *(uint4*)(base + 8);
    float x0,x1,x2,x3,x4,x5,x6,x7;
    unpack2(v0.x, x0, x1); unpack2(v0.y, x2, x3);
    unpack2(v0.z, x4, x5); unpack2(v0.w, x6, x7);
    v0.x = packb(__expf(x0 - M) * inv, __expf(x1 - M) * inv);
    v0.y = packb(__expf(x2 - M) * inv, __expf(x3 - M) * inv);
    v0.z = packb(__expf(x4 - M) * inv, __expf(x5 - M) * inv);
    v0.w = packb(__expf(x6 - M) * inv, __expf(x7 - M) * inv);
    unpack2(v1.x, x0, x1); unpack2(v1.y, x2, x3);
    unpack2(v1.z, x4, x5); unpack2(v1.w, x6, x7);
    v1.x = packb(__expf(x0 - M) * inv, __expf(x1 - M) * inv);
    v1.y = packb(__expf(x2 - M) * inv, __expf(x3 - M) * inv);
    v1.z = packb(__expf(x4 - M) * inv, __expf(x5 - M) * inv);
    v1.w = packb(__expf(x6 - M) * inv, __expf(x7 - M) * inv);
    *(uint4*)base = v0;
    *(uint4*)(base + 8) = v1;
    base += 4096;
  }
}

// ---------------------------------------------------------------------------
// G2: ctx partials = attn @ X. Pure gload16 staging for A and B (both packed
// linear). BK=64, K-split x2. grid (8 z, 8 nty, 4mt*2s).
// ---------------------------------------------------------------------------
__global__ __launch_bounds__(256) void gemm2p(
    const ushort* __restrict__ At, const ushort* __restrict__ Xp2,
    float* __restrict__ P) {
  __shared__ alignas(16) ushort sA[8192];
  __shared__ alignas(16) ushort sB[8192];
  const int z = blockIdx.x, nty = blockIdx.y;
  const int mt = blockIdx.z & 3, s = blockIdx.z >> 2;
  const int tid = threadIdx.x;
  const int wave = tid >> 6, lane = tid & 63;
  const int wm = wave >> 1, wn = wave & 1;
  const int fr = lane & 15, fq = lane >> 4;
  const int sfr = swz(fr);

  const ushort* Ab = At + (size_t)(z * 4 + mt) * 524288 + (size_t)s * 262144;
  const ushort* Bb = Xp2 + ((size_t)(z * 8 + nty) * 128 + s * 64) * 4096;

  f32x4 acc[4][4];
#pragma unroll
  for (int a = 0; a < 4; ++a)
#pragma unroll
    for (int c = 0; c < 4; ++c) acc[a][c] = (f32x4){0.f, 0.f, 0.f, 0.f};

  for (int it = 0; it < 32; ++it) {
#pragma unroll
    for (int j = 0; j < 4; ++j) {
      gload16(Bb + (size_t)it * 8192 + wave * 2048 + j * 512 + lane * 8,
              &sB[wave * 2048 + j * 512]);
      gload16(Ab + (size_t)it * 8192 + wave * 2048 + j * 512 + lane * 8,
              &sA[wave * 2048 + j * 512]);
    }
    __syncthreads();
#pragma unroll
    for (int kk = 0; kk < 2; ++kk) {
      bf16x8 aF[4], bF[4];
#pragma unroll
      for (int u = 0; u < 4; ++u) {
        aF[u] = *(const bf16x8*)&sA[kk * 4096 + ((wm << 6) + (u << 4) + fr) * 32 + ((fq ^ sfr) << 3)];
        bF[u] = *(const bf16x8*)&sB[kk * 4096 + ((wn << 6) + (u << 4) + fr) * 32 + ((fq ^ sfr) << 3)];
      }
#pragma unroll
      for (int mi = 0; mi < 4; ++mi)
#pragma unroll
        for (int ni = 0; ni < 4; ++ni)
          acc[mi][ni] = __builtin_amdgcn_mfma_f32_16x16x32_bf16(
              aF[mi], bF[ni], acc[mi][ni], 0, 0, 0);
    }
    __syncthreads();
  }

  float* Pb = P + (((size_t)(s * 8 + z) * 512) + mt * 128) * 1024 + nty * 128;
#pragma unroll
  for (int mi = 0; mi < 4; ++mi)
#pragma unroll
    for (int ni = 0; ni < 4; ++ni)
#pragma unroll
      for (int r = 0; r < 4; ++r) {
        const int row = (wm << 6) + (mi << 4) + (fq << 2) + r;
        const int col = (wn << 6) + (ni << 4) + fr;
        Pb[(size_t)row * 1024 + col] = acc[mi][ni][r];
      }
}

// ---------------------------------------------------------------------------
// ctxwv_gemm: folds P0+P1 sum into A-staging; per (ks,h,b) partial
// tmp2 = ctx @ Wv_h. -> P2 fp32 [4][256][1024].
// ---------------------------------------------------------------------------
__global__ __launch_bounds__(256) void ctxwv_gemm(
    const float* __restrict__ P, const ushort* __restrict__ WvT,
    float* __restrict__ P2) {
  __shared__ alignas(16) ushort sA[32 * 264];
  __shared__ alignas(16) ushort sB[64 * 264];
  const int ks = blockIdx.x, h = blockIdx.y, b = blockIdx.z;
  const int kb = ks << 8;
  const int t = threadIdx.x;
#pragma unroll
  for (int q = 0; q < 4; ++q) {
    const int i = t >> 3, seg = ((t & 7) + q * 8) << 3;
    const float* p0 = P + ((size_t)(0 * 8 + b) * 512 + h * 32 + i) * 1024 + kb + seg;
    const float* p1 = P + ((size_t)(1 * 8 + b) * 512 + h * 32 + i) * 1024 + kb + seg;
    const float4 a0 = *(const float4*)p0,       a1 = *(const float4*)(p0 + 4);
    const float4 b0 = *(const float4*)p1,       b1 = *(const float4*)(p1 + 4);
    uint4 o;
    o.x = packb(a0.x + b0.x, a0.y + b0.y);
    o.y = packb(a0.z + b0.z, a0.w + b0.w);
    o.z = packb(a1.x + b1.x, a1.y + b1.y);
    o.w = packb(a1.z + b1.z, a1.w + b1.w);
    *(uint4*)&sA[i * 264 + seg] = o;
  }
#pragma unroll
  for (int p = 0; p < 8; ++p) {
    const int rr = (t >> 3) + (p & 1) * 32;
    const int seg = ((t & 7) + (p >> 1) * 8) << 3;
    *(uint4*)&sB[rr * 264 + seg] =
        *(const uint4*)(WvT + (size_t)(h * 64 + rr) * 1024 + kb + seg);
  }
  __syncthreads();

  const int wave = t >> 6, lane = t & 63;
  const int fr = lane & 15, fq = lane >> 4;
  f32x4 acc[2];
  acc[0] = (f32x4){0.f, 0.f, 0.f, 0.f};
  acc[1] = (f32x4){0.f, 0.f, 0.f, 0.f};

#pragma unroll
  for (int ki = 0; ki < 8; ++ki) {
    bf16x8 bFr = *(const bf16x8*)&sB[((wave << 4) + fr) * 264 + (ki << 5) + (fq << 3)];
#pragma unroll
    for (int mi = 0; mi < 2; ++mi) {
      bf16x8 aF = *(const bf16x8*)&sA[((mi << 4) + fr) * 264 + (ki << 5) + (fq << 3)];
      acc[mi] = __builtin_amdgcn_mfma_f32_16x16x32_bf16(aF, bFr, acc[mi], 0, 0, 0);
    }
  }
  float* dst = P2 + (size_t)ks * 262144;
#pragma unroll
  for (int mi = 0; mi < 2; ++mi)
#pragma unroll
    for (int rr = 0; rr < 4; ++rr) {
      const int row = b * 32 + (mi << 4) + (fq << 2) + rr;
      const int col = h * 64 + (wave << 4) + fr;
      dst[(size_t)row * 1024 + col] = acc[mi][rr];
    }
}

// ---------------------------------------------------------------------------
// out_gemm: folds P2 4-way sum into A-staging; out partials = tmp2 @ Wo,
// K-split x4 -> O4 fp32. grid (8,2,4).
// ---------------------------------------------------------------------------
__global__ __launch_bounds__(256) void out_gemm(
    const float* __restrict__ P2, const ushort* __restrict__ WoT,
    float* __restrict__ O4) {
  __shared__ alignas(16) ushort sA[128 * 40];
  __shared__ alignas(16) ushort sB[128 * 40];
  const int nt = blockIdx.x, mt = blockIdx.y, ks = blockIdx.z;
  const int m0 = mt << 7, n0 = nt << 7, kb = ks << 8;
  const int t = threadIdx.x;
  const int wave = t >> 6, lane = t & 63;
  const int wm = wave >> 1, wn = wave & 1;
  const int fr = lane & 15, fq = lane >> 4;
  const int r = t >> 1, sg = (t & 1) << 4;

  f32x4 acc[4][4];
#pragma unroll
  for (int a = 0; a < 4; ++a)
#pragma unroll
    for (int c = 0; c < 4; ++c) acc[a][c] = (f32x4){0.f, 0.f, 0.f, 0.f};

  for (int it = 0; it < 8; ++it) {
    const int k0 = kb + (it << 5);
    {
      float s[16];
#pragma unroll
      for (int j = 0; j < 16; ++j) s[j] = 0.f;
#pragma unroll
      for (int p = 0; p < 4; ++p) {
        const float* base = P2 + (size_t)p * 262144 + (size_t)(m0 + r) * 1024 + k0 + sg;
#pragma unroll
        for (int q = 0; q < 4; ++q) {
          const float4 v = *(const float4*)(base + q * 4);
          s[q*4+0] += v.x; s[q*4+1] += v.y; s[q*4+2] += v.z; s[q*4+3] += v.w;
        }
      }
      uint4 o0, o1;
      o0.x = packb(s[0], s[1]);   o0.y = packb(s[2], s[3]);
      o0.z = packb(s[4], s[5]);   o0.w = packb(s[6], s[7]);
      o1.x = packb(s[8], s[9]);   o1.y = packb(s[10], s[11]);
      o1.z = packb(s[12], s[13]); o1.w = packb(s[14], s[15]);
      *(uint4*)&sA[r * 40 + sg]     = o0;
      *(uint4*)&sA[r * 40 + sg + 8] = o1;
    }
    {
      const uint4* s4 = (const uint4*)(WoT + (size_t)(n0 + r) * 1024 + k0 + sg);
      *(uint4*)&sB[r * 40 + sg]     = s4[0];
      *(uint4*)&sB[r * 40 + sg + 8] = s4[1];
    }
    __syncthreads();
    bf16x8 aF[4], bF[4];
#pragma unroll
    for (int u = 0; u < 4; ++u) {
      aF[u] = *(const bf16x8*)&sA[((wm << 6) + (u << 4) + fr) * 40 + (fq << 3)];
      bF[u] = *(const bf16x8*)&sB[((wn << 6) + (u << 4) + fr) * 40 + (fq << 3)];
    }
#pragma unroll
    for (int mi = 0; mi < 4; ++mi)
#pragma unroll
      for (int ni = 0; ni < 4; ++ni)
        acc[mi][ni] = __builtin_amdgcn_mfma_f32_16x16x32_bf16(
            aF[mi], bF[ni], acc[mi][ni], 0, 0, 0);
    __syncthreads();
  }
  float* dst = O4 + (size_t)ks * 262144;
#pragma unroll
  for (int mi = 0; mi < 4; ++mi)
#pragma unroll
    for (int ni = 0; ni < 4; ++ni)
#pragma unroll
      for (int rr = 0; rr < 4; ++rr) {
        const int row = m0 + (wm << 6) + (mi << 4) + (fq << 2) + rr;
        const int col = n0 + (wn << 6) + (ni << 4) + fr;
        dst[(size_t)row * 1024 + col] = acc[mi][ni][rr];
      }
}

// ---------------------------------------------------------------------------
__global__ __launch_bounds__(256) void sum_out4(
    const float* __restrict__ O4, float* __restrict__ out) {
  const size_t i4 = ((size_t)blockIdx.x * 256 + threadIdx.x) * 4;
  float4 acc = *(const float4*)(O4 + i4);
#pragma unroll
  for (int p = 1; p < 4; ++p) {
    const float4 v = *(const float4*)(O4 + (size_t)p * 262144 + i4);
    acc.x += v.x; acc.y += v.y; acc.z += v.z; acc.w += v.w;
  }
  *(float4*)(out + i4) = acc;
}

// ---------------------------------------------------------------------------
extern "C" void kernel_launch(void* const* d_in, const int* in_sizes, int n_in,
                              void* d_out, int out_size, void* d_ws, size_t ws_size,
                              hipStream_t stream) {
  const float* hs  = (const float*)d_in[0];
  const float* enc = (const float*)d_in[1];
  const int*   pos = (const int*)d_in[2];
  const float* Wq  = (const float*)d_in[3];
  const float* Wk  = (const float*)d_in[4];
  const float* Wv  = (const float*)d_in[5];
  const float* Wo  = (const float*)d_in[6];
  float* out = (float*)d_out;

  char* w = (char*)d_ws;
  ushort* Xp1  = (ushort*)w;               // gemm1 B (67 MB)
  float*  P    = (float*)w;                // ALIAS: gemm2p partials 33.5MB (Xp1 dead)
  w += (size_t)67108864;
  ushort* Xp2  = (ushort*)w;               // gemm2p B (67 MB)
  float*  P2   = (float*)w;                // ALIAS: ctxwv partials 4MB (Xp2 dead)
  w += (size_t)67108864;
  ushort* qk   = (ushort*)w; w += (size_t)8388608;    // [8][512][1024] bf16
  ushort* Sc   = (ushort*)w; w += (size_t)33554432;   // packed scores -> attn
  float2* pstat  = (float2*)w; w += (size_t)1048576;
  float*  qP   = (float*)w;                // [4][256][1024] fp32
  float*  O4   = (float*)w;                // ALIAS (qP dead after qk_rope_gemm)
  w += (size_t)4194304;
  ushort* WqT = (ushort*)w; w += (size_t)2097152;
  ushort* Wkb = (ushort*)w; w += (size_t)2097152;
  ushort* WvT = (ushort*)w; w += (size_t)2097152;
  ushort* WoT = (ushort*)w; w += (size_t)2097152;

  pack_all<<<dim3(16, 32, 10), 256, 0, stream>>>(enc, Xp1, Xp2,
      Wq, Wk, Wv, Wo, WqT, Wkb, WvT, WoT);
  qrope_gemm<<<dim3(8, 2, 4), 256, 0, stream>>>(hs, WqT, qP);
  qk_rope_gemm<<<dim3(4, 16, 8), 256, 0, stream>>>(qP, Wkb, pos, qk);
  gemm1<<<dim3(8, 32, 4), 256, 0, stream>>>(qk, Xp1, Sc, pstat);
  softmax_apply2<<<dim3(32, 16), 256, 0, stream>>>(Sc, pstat);
  gemm2p<<<dim3(8, 8, 8), 256, 0, stream>>>(Sc, Xp2, P);
  ctxwv_gemm<<<dim3(4, 16, 8), 256, 0, stream>>>(P, WvT, P2);
  out_gemm<<<dim3(8, 2, 4), 256, 0, stream>>>(P2, WoT, O4);
  sum_out4<<<256, 256, 0, stream>>>(O4, out);
}